// Round 2
// baseline (2013.518 us; speedup 1.0000x reference)
//
#include <hip/hip_runtime.h>
#include <hip/hip_bf16.h>
#include <math.h>

#define L4K 4096

// ---------------- K1: pre-LN + bott_in + in_proj ----------------
__global__ __launch_bounds__(256) void k1_pre(
    const float* __restrict__ x, const float* __restrict__ png, const float* __restrict__ pnb,
    const float* __restrict__ biw, const float* __restrict__ bib, const float* __restrict__ ipw,
    float* __restrict__ zc, float* __restrict__ xcp, float* __restrict__ zg)
{
    __shared__ float xs[128*32];   // [c][i], 32 tokens
    __shared__ float wl[64*128];   // bott_in_w [j][c]
    __shared__ float zs[32*65];    // z per token (padded)
    __shared__ float ipl[64*16];   // in_proj_w
    __shared__ float pngs[128], pnbs[128];
    int tid = threadIdx.x;
    int l0 = blockIdx.x*32, b = blockIdx.y;
    const float* xb = x + (size_t)b*128*L4K;
    for (int it = 0; it < 16; ++it) {
        int f = it*256 + tid; int c = f>>5, i = f&31;
        xs[f] = xb[(size_t)c*L4K + l0 + i];
    }
    for (int f = tid; f < 8192; f += 256) wl[f] = biw[f];
    for (int f = tid; f < 1024; f += 256) ipl[f] = ipw[f];
    if (tid < 128) { pngs[tid] = png[tid]; pnbs[tid] = pnb[tid]; }
    __syncthreads();
    int i = tid & 31, q = tid >> 5;   // q in 0..7, 8 outputs each
    float s = 0.f, s2 = 0.f;
    for (int c = 0; c < 128; ++c) { float v = xs[c*32+i]; s += v; s2 = fmaf(v,v,s2); }
    float mn = s*(1.f/128.f);
    float rstd = rsqrtf(s2*(1.f/128.f) - mn*mn + 1e-5f);
    float z[8];
    #pragma unroll
    for (int jj = 0; jj < 8; ++jj) z[jj] = bib[q*8+jj];
    for (int c = 0; c < 128; ++c) {
        float xv = (xs[c*32+i] - mn)*rstd*pngs[c] + pnbs[c];
        #pragma unroll
        for (int jj = 0; jj < 8; ++jj) z[jj] = fmaf(xv, wl[(q*8+jj)*128 + c], z[jj]);
    }
    #pragma unroll
    for (int jj = 0; jj < 8; ++jj) zs[i*65 + q*8 + jj] = z[jj];
    __syncthreads();
    if (tid < 128) {
        int i2 = tid & 31, g = tid >> 5;   // g = chunk 0..3
        int n = g*8 + b; int l = l0 + i2;
        float zv[16];
        #pragma unroll
        for (int k = 0; k < 16; ++k) zv[k] = zs[i2*65 + g*16 + k];
        size_t tb = (size_t)n*L4K + l;
        float4* zc4 = (float4*)(zc + tb*16);
        zc4[0] = make_float4(zv[0],zv[1],zv[2],zv[3]);
        zc4[1] = make_float4(zv[4],zv[5],zv[6],zv[7]);
        zc4[2] = make_float4(zv[8],zv[9],zv[10],zv[11]);
        zc4[3] = make_float4(zv[12],zv[13],zv[14],zv[15]);
        float* xo = xcp + tb*32;
        float* zo = zg + tb*32;
        #pragma unroll
        for (int o = 0; o < 64; ++o) {
            float a = 0.f;
            #pragma unroll
            for (int k = 0; k < 16; ++k) a = fmaf(zv[k], ipl[o*16+k], a);
            if (o < 32) xo[o] = a; else zo[o-32] = a;
        }
    }
}

// ---------------- K2: conv + silu + x_proj + dt + scan records ----------------
__global__ __launch_bounds__(128) void k2_conv(
    const float* __restrict__ xcp, const float* __restrict__ cw, const float* __restrict__ cb,
    const float* __restrict__ xpw, const float* __restrict__ dtw, const float* __restrict__ dtb,
    float* __restrict__ S)
{
    __shared__ float xt[131*33];
    __shared__ float cwl[128], cbl[32], xpl[33*32], dtwl[32], dtbl[32];
    int tid = threadIdx.x;
    int t0 = blockIdx.x*128; int n = blockIdx.y;
    const float* xb = xcp + (size_t)n*L4K*32;
    for (int f = tid; f < 131*32; f += 128) {
        int r = f >> 5, d = f & 31;
        int t = t0 - 3 + r;
        xt[r*33 + d] = (t >= 0) ? xb[(size_t)t*32 + d] : 0.f;
    }
    if (tid < 128) cwl[tid] = cw[tid];
    if (tid < 32) { cbl[tid] = cb[tid]; dtwl[tid] = dtw[tid]; dtbl[tid] = dtb[tid]; }
    for (int f = tid; f < 33*32; f += 128) xpl[f] = xpw[f];
    __syncthreads();
    int t = t0 + tid;
    float xc[32];
    #pragma unroll
    for (int d = 0; d < 32; ++d) {
        float sv = cbl[d];
        #pragma unroll
        for (int k = 0; k < 4; ++k) sv = fmaf(cwl[d*4+k], xt[(tid+k)*33 + d], sv);
        xc[d] = sv / (1.f + __expf(-sv));   // silu
    }
    float dtr = 0.f; float Bv[16], Cv[16];
    #pragma unroll
    for (int dd = 0; dd < 32; ++dd) dtr = fmaf(xc[dd], xpl[dd], dtr);
    #pragma unroll
    for (int o = 0; o < 16; ++o) {
        float a = 0.f, a2 = 0.f;
        #pragma unroll
        for (int dd = 0; dd < 32; ++dd) {
            a  = fmaf(xc[dd], xpl[(1+o)*32+dd],  a);
            a2 = fmaf(xc[dd], xpl[(17+o)*32+dd], a2);
        }
        Bv[o] = a; Cv[o] = a2;
    }
    float* r = S + ((size_t)n*L4K + t)*128;
    #pragma unroll
    for (int d = 0; d < 32; ++d) {
        float dv = fmaf(dtr, dtwl[d], dtbl[d]);
        float sp = fmaxf(dv, 0.f) + log1pf(__expf(-fabsf(dv)));  // softplus
        r[d]      = sp;
        r[32 + d] = sp * xc[d];
        r[96 + d] = xc[d];
    }
    #pragma unroll
    for (int o = 0; o < 16; ++o) { r[64+o] = Bv[o]; r[80+o] = Cv[o]; }
}

// ---------------- K3: selective scan ----------------
__global__ __launch_bounds__(64) void k3_scan(
    const float* __restrict__ S, const float* __restrict__ alog, float* __restrict__ y)
{
    int lane = threadIdx.x;
    int grp = lane >> 4, sidx = lane & 15;
    int pair = blockIdx.x*4 + grp;          // (n,d) flat
    int n = pair >> 5, d = pair & 31;
    float A = -__expf(alog[d*16 + sidx]);
    const float* Sp = S + (size_t)n*L4K*128;
    float* yp = y + (size_t)n*L4K*32;
    float h = 0.f;
    #pragma unroll 4
    for (int t = 0; t < L4K; ++t) {
        const float* r = Sp + (size_t)t*128;
        float dtv = r[d], dxv = r[32+d], Bvv = r[64+sidx], Cvv = r[80+sidx];
        float dA = __expf(dtv * A);
        h = fmaf(dA, h, dxv * Bvv);
        float p = h * Cvv;
        p += __shfl_xor(p, 8, 16);
        p += __shfl_xor(p, 4, 16);
        p += __shfl_xor(p, 2, 16);
        p += __shfl_xor(p, 1, 16);
        if (sidx == 0) yp[(size_t)t*32 + d] = p;
    }
}

// ---------------- K5: gate + out_proj + residual -> m ----------------
__global__ __launch_bounds__(256) void k5_out(
    const float* __restrict__ y, const float* __restrict__ S, const float* __restrict__ zg,
    const float* __restrict__ zc, const float* __restrict__ Dp, const float* __restrict__ opw,
    float* __restrict__ m)
{
    int id = blockIdx.x*256 + threadIdx.x;  // 0..131071  (n,t)
    int n = id >> 12, t = id & 4095;
    const float* yp  = y  + (size_t)id*32;
    const float* xcr = S  + (size_t)id*128 + 96;
    const float* zgp = zg + (size_t)id*32;
    const float* zcp = zc + (size_t)id*16;
    float v[32];
    #pragma unroll
    for (int dd = 0; dd < 32; ++dd) {
        float g = zgp[dd];
        float sig = 1.f/(1.f + __expf(-g));
        v[dd] = (yp[dd] + xcr[dd]*Dp[dd]) * (g*sig);
    }
    int b = n & 7, g4 = n >> 3;
    float* mp = m + ((size_t)b*L4K + t)*64 + g4*16;
    #pragma unroll
    for (int j = 0; j < 16; ++j) {
        float a = zcp[j];
        #pragma unroll
        for (int dd = 0; dd < 32; ++dd) a = fmaf(v[dd], opw[j*32+dd], a);
        mp[j] = a;
    }
}

// ---------------- K6: post-LN + bott_out + out_pre = 2x + token ----------------
__global__ __launch_bounds__(256) void k6_post(
    const float* __restrict__ m, const float* __restrict__ x,
    const float* __restrict__ pog, const float* __restrict__ pob,
    const float* __restrict__ bow, const float* __restrict__ bob,
    const float* __restrict__ rsp, float* __restrict__ outp)
{
    __shared__ float ms[64*65];
    __shared__ float wl[128*64];   // bott_out_w [c][j]
    __shared__ float pogs[64], pobs[64];
    int tid = threadIdx.x;
    int l0 = blockIdx.x*64, b = blockIdx.y;
    const float* mb = m + ((size_t)b*L4K + l0)*64;
    for (int f = tid; f < 4096; f += 256) {
        int i = f>>6, j = f&63;
        ms[i*65 + j] = mb[f];
    }
    for (int f = tid; f < 8192; f += 256) wl[f] = bow[f];
    if (tid < 64) { pogs[tid] = pog[tid]; pobs[tid] = pob[tid]; }
    __syncthreads();
    float rs = rsp[0];
    int i = tid & 63, q = tid >> 6;   // q: 32 channels each
    float s = 0.f, s2 = 0.f;
    for (int j = 0; j < 64; ++j) { float v = ms[i*65+j]; s += v; s2 = fmaf(v,v,s2); }
    float mn = s*(1.f/64.f);
    float rstd = rsqrtf(s2*(1.f/64.f) - mn*mn + 1e-5f);
    float acc[32];
    #pragma unroll
    for (int cc = 0; cc < 32; ++cc) acc[cc] = bob[q*32+cc];
    for (int j = 0; j < 64; ++j) {
        float v = (ms[i*65+j]-mn)*rstd*pogs[j] + pobs[j];
        #pragma unroll
        for (int cc = 0; cc < 32; ++cc) acc[cc] = fmaf(v, wl[(q*32+cc)*64+j], acc[cc]);
    }
    const float* xb = x + (size_t)b*128*L4K + l0 + i;
    float* ob = outp + (size_t)b*128*L4K + l0 + i;
    #pragma unroll
    for (int cc = 0; cc < 32; ++cc) {
        int c = q*32 + cc;
        ob[(size_t)c*L4K] = 2.f*xb[(size_t)c*L4K] + acc[cc]*rs;
    }
}

// ---------------- GEMM helpers ----------------
#define FMA4(acc, sc, v) { acc.x = fmaf(sc, v.x, acc.x); acc.y = fmaf(sc, v.y, acc.y); acc.z = fmaf(sc, v.z, acc.z); acc.w = fmaf(sc, v.w, acc.w); }

// ---------------- K7: fc1 (512x128 @ [128 x 4096]) ----------------
__global__ __launch_bounds__(256) void k7_fc1(
    const float* __restrict__ ap, const float* __restrict__ w, float* __restrict__ h1)
{
    __shared__ float ws_w[64*128];  // [oo][k]
    __shared__ float bs[128*64];    // [k][ll]
    int tid = threadIdx.x;
    int l0 = blockIdx.x*64, o0 = blockIdx.y*64, b = blockIdx.z;
    for (int f = tid; f < 8192; f += 256) {
        int oo = f>>7, k = f&127;
        ws_w[f] = w[(size_t)(o0+oo)*128 + k];
    }
    for (int f = tid; f < 8192; f += 256) {
        int k = f>>6, ll = f&63;
        bs[f] = ap[(size_t)b*128*L4K + (size_t)k*L4K + l0 + ll];
    }
    __syncthreads();
    int tl = tid & 15, to = tid >> 4;
    float4 acc0 = make_float4(0,0,0,0), acc1 = acc0, acc2 = acc0, acc3 = acc0;
    for (int k = 0; k < 128; k += 4) {
        float4 a0 = *(const float4*)&ws_w[(to*4+0)*128 + k];
        float4 a1 = *(const float4*)&ws_w[(to*4+1)*128 + k];
        float4 a2 = *(const float4*)&ws_w[(to*4+2)*128 + k];
        float4 a3 = *(const float4*)&ws_w[(to*4+3)*128 + k];
        float4 v0 = *(const float4*)&bs[(k+0)*64 + tl*4];
        float4 v1 = *(const float4*)&bs[(k+1)*64 + tl*4];
        float4 v2 = *(const float4*)&bs[(k+2)*64 + tl*4];
        float4 v3 = *(const float4*)&bs[(k+3)*64 + tl*4];
        FMA4(acc0, a0.x, v0) FMA4(acc0, a0.y, v1) FMA4(acc0, a0.z, v2) FMA4(acc0, a0.w, v3)
        FMA4(acc1, a1.x, v0) FMA4(acc1, a1.y, v1) FMA4(acc1, a1.z, v2) FMA4(acc1, a1.w, v3)
        FMA4(acc2, a2.x, v0) FMA4(acc2, a2.y, v1) FMA4(acc2, a2.z, v2) FMA4(acc2, a2.w, v3)
        FMA4(acc3, a3.x, v0) FMA4(acc3, a3.y, v1) FMA4(acc3, a3.z, v2) FMA4(acc3, a3.w, v3)
    }
    float* hb = h1 + (size_t)b*512*L4K + (size_t)(o0 + to*4)*L4K + l0 + tl*4;
    *(float4*)&hb[0]        = acc0;
    *(float4*)&hb[L4K]      = acc1;
    *(float4*)&hb[2*L4K]    = acc2;
    *(float4*)&hb[3*L4K]    = acc3;
}

// ---------------- K10: fc2 (128x512 @ [512 x 4096]) ----------------
__global__ __launch_bounds__(256) void k10_fc2(
    const float* __restrict__ h1, const float* __restrict__ w, float* __restrict__ h2)
{
    __shared__ float ws_w[64*128];
    __shared__ float bs[128*64];
    int tid = threadIdx.x;
    int l0 = blockIdx.x*64, o0 = blockIdx.y*64, b = blockIdx.z;
    int tl = tid & 15, to = tid >> 4;
    float4 acc0 = make_float4(0,0,0,0), acc1 = acc0, acc2 = acc0, acc3 = acc0;
    for (int kc = 0; kc < 4; ++kc) {
        if (kc) __syncthreads();
        for (int f = tid; f < 8192; f += 256) {
            int oo = f>>7, k = f&127;
            ws_w[f] = w[(size_t)(o0+oo)*512 + kc*128 + k];
        }
        for (int f = tid; f < 8192; f += 256) {
            int k = f>>6, ll = f&63;
            bs[f] = h1[(size_t)b*512*L4K + (size_t)(kc*128+k)*L4K + l0 + ll];
        }
        __syncthreads();
        for (int k = 0; k < 128; k += 4) {
            float4 a0 = *(const float4*)&ws_w[(to*4+0)*128 + k];
            float4 a1 = *(const float4*)&ws_w[(to*4+1)*128 + k];
            float4 a2 = *(const float4*)&ws_w[(to*4+2)*128 + k];
            float4 a3 = *(const float4*)&ws_w[(to*4+3)*128 + k];
            float4 v0 = *(const float4*)&bs[(k+0)*64 + tl*4];
            float4 v1 = *(const float4*)&bs[(k+1)*64 + tl*4];
            float4 v2 = *(const float4*)&bs[(k+2)*64 + tl*4];
            float4 v3 = *(const float4*)&bs[(k+3)*64 + tl*4];
            FMA4(acc0, a0.x, v0) FMA4(acc0, a0.y, v1) FMA4(acc0, a0.z, v2) FMA4(acc0, a0.w, v3)
            FMA4(acc1, a1.x, v0) FMA4(acc1, a1.y, v1) FMA4(acc1, a1.z, v2) FMA4(acc1, a1.w, v3)
            FMA4(acc2, a2.x, v0) FMA4(acc2, a2.y, v1) FMA4(acc2, a2.z, v2) FMA4(acc2, a2.w, v3)
            FMA4(acc3, a3.x, v0) FMA4(acc3, a3.y, v1) FMA4(acc3, a3.z, v2) FMA4(acc3, a3.w, v3)
        }
    }
    float* hb = h2 + (size_t)b*128*L4K + (size_t)(o0 + to*4)*L4K + l0 + tl*4;
    *(float4*)&hb[0]     = acc0;
    *(float4*)&hb[L4K]   = acc1;
    *(float4*)&hb[2*L4K] = acc2;
    *(float4*)&hb[3*L4K] = acc3;
}

// ---------------- GroupNorm stats (generic) ----------------
__global__ __launch_bounds__(256) void k_gnstats(
    const float* __restrict__ h, float* __restrict__ stats, int per_group)
{
    __shared__ float sred[256], sred2[256];
    int bid = blockIdx.x, tid = threadIdx.x;
    const float4* base = (const float4*)(h + (size_t)bid*per_group);
    int n4 = per_group >> 2;
    float s = 0.f, s2 = 0.f;
    for (int i = tid; i < n4; i += 256) {
        float4 v = base[i];
        s += v.x+v.y+v.z+v.w;
        s2 = fmaf(v.x,v.x,s2); s2 = fmaf(v.y,v.y,s2); s2 = fmaf(v.z,v.z,s2); s2 = fmaf(v.w,v.w,s2);
    }
    sred[tid] = s; sred2[tid] = s2; __syncthreads();
    for (int off = 128; off; off >>= 1) {
        if (tid < off) { sred[tid] += sred[tid+off]; sred2[tid] += sred2[tid+off]; }
        __syncthreads();
    }
    if (tid == 0) {
        float inv = 1.f/(float)per_group;
        float mn = sred[0]*inv;
        float var = sred2[0]*inv - mn*mn;
        stats[bid*2]   = mn;
        stats[bid*2+1] = rsqrtf(var + 1e-5f);
    }
}

// ---------------- K9: gn1 apply + exact gelu (in place on h1) ----------------
__global__ __launch_bounds__(256) void k9_gngelu(
    float* __restrict__ h1, const float* __restrict__ stats,
    const float* __restrict__ g1, const float* __restrict__ b1)
{
    int f = blockIdx.x*256 + threadIdx.x;   // float4 index, total 4194304
    int e = f*4;
    int c = (e >> 12) & 511;
    int b = e >> 21;
    int sg = b*32 + (c >> 4);
    float mn = stats[sg*2], rstd = stats[sg*2+1];
    float gv = g1[c], bv = b1[c];
    float4 v = ((float4*)h1)[f];
    float t0 = (v.x-mn)*rstd*gv + bv;
    float t1 = (v.y-mn)*rstd*gv + bv;
    float t2 = (v.z-mn)*rstd*gv + bv;
    float t3 = (v.w-mn)*rstd*gv + bv;
    v.x = 0.5f*t0*(1.f + erff(t0*0.70710678118654752f));
    v.y = 0.5f*t1*(1.f + erff(t1*0.70710678118654752f));
    v.z = 0.5f*t2*(1.f + erff(t2*0.70710678118654752f));
    v.w = 0.5f*t3*(1.f + erff(t3*0.70710678118654752f));
    ((float4*)h1)[f] = v;
}

// ---------------- K12: final out = out_pre + gn2(h2) ----------------
__global__ __launch_bounds__(256) void k12_final(
    const float* __restrict__ outp, const float* __restrict__ h2,
    const float* __restrict__ stats, const float* __restrict__ g2,
    const float* __restrict__ b2, float* __restrict__ out)
{
    int f = blockIdx.x*256 + threadIdx.x;   // float4 index, total 1048576
    int e = f*4;
    int c = (e >> 12) & 127;
    int b = e >> 19;
    int sg = b*32 + (c >> 2);
    float mn = stats[sg*2], rstd = stats[sg*2+1];
    float gv = g2[c], bv = b2[c];
    float4 o = ((const float4*)outp)[f];
    float4 h = ((const float4*)h2)[f];
    float4 r;
    r.x = o.x + (h.x-mn)*rstd*gv + bv;
    r.y = o.y + (h.y-mn)*rstd*gv + bv;
    r.z = o.z + (h.z-mn)*rstd*gv + bv;
    r.w = o.w + (h.w-mn)*rstd*gv + bv;
    ((float4*)out)[f] = r;
}

extern "C" void kernel_launch(void* const* d_in, const int* in_sizes, int n_in,
                              void* d_out, int out_size, void* d_ws, size_t ws_size,
                              hipStream_t stream) {
    (void)in_sizes; (void)n_in; (void)out_size; (void)ws_size;
    const float* x    = (const float*)d_in[0];
    const float* png  = (const float*)d_in[1];
    const float* pnb  = (const float*)d_in[2];
    const float* biw  = (const float*)d_in[3];
    const float* bib  = (const float*)d_in[4];
    const float* ipw  = (const float*)d_in[5];
    const float* cw   = (const float*)d_in[6];
    const float* cb   = (const float*)d_in[7];
    const float* xpw  = (const float*)d_in[8];
    const float* dtw  = (const float*)d_in[9];
    const float* dtb  = (const float*)d_in[10];
    const float* alog = (const float*)d_in[11];
    const float* Dp   = (const float*)d_in[12];
    const float* opw  = (const float*)d_in[13];
    const float* pog  = (const float*)d_in[14];
    const float* pob  = (const float*)d_in[15];
    const float* bow  = (const float*)d_in[16];
    const float* bob  = (const float*)d_in[17];
    const float* rsp  = (const float*)d_in[18];
    const float* f1w  = (const float*)d_in[19];
    const float* g1g  = (const float*)d_in[20];
    const float* g1b  = (const float*)d_in[21];
    const float* f2w  = (const float*)d_in[22];
    const float* g2g  = (const float*)d_in[23];
    const float* g2b  = (const float*)d_in[24];

    char* ws = (char*)d_ws;
    // Layout (bytes), with aliasing across phases:
    float* S    = (float*)(ws + 0);           // 64 MB  (records, dead after k5)
    float* zc   = (float*)(ws + 67108864);    // 8 MB   (dead after k5)
    float* zg   = (float*)(ws + 75497472);    // 16 MB  (dead after k5)
    float* xcp  = (float*)(ws + 92274688);    // 16 MB  (dead after k2)
    float* y    = (float*)(ws + 92274688);    // reuses xcp (k3 after k2)
    float* m    = (float*)(ws + 109051904);   // 8 MB   (dead after k6) -> peak 112 MB
    float* outp = (float*)(ws + 0);           // 16 MB  (post phase, aliases S)
    float* h1   = (float*)(ws + 16777216);    // 64 MB  (aliases S)
    float* h2   = (float*)(ws + 83886080);    // 16 MB  (aliases zg/y, dead regions)
    float* st1  = (float*)(ws + 100663296);
    float* st2  = (float*)(ws + 100728832);

    k1_pre<<<dim3(128,8),256,0,stream>>>(x,png,pnb,biw,bib,ipw,zc,xcp,zg);
    k2_conv<<<dim3(32,32),128,0,stream>>>(xcp,cw,cb,xpw,dtw,dtb,S);
    k3_scan<<<256,64,0,stream>>>(S,alog,y);
    k5_out<<<512,256,0,stream>>>(y,S,zg,zc,Dp,opw,m);
    k6_post<<<dim3(64,8),256,0,stream>>>(m,x,pog,pob,bow,bob,rsp,outp);
    k7_fc1<<<dim3(64,8,8),256,0,stream>>>(outp,f1w,h1);
    k_gnstats<<<256,256,0,stream>>>(h1,st1,65536);
    k9_gngelu<<<16384,256,0,stream>>>(h1,st1,g1g,g1b);
    k10_fc2<<<dim3(64,2,8),256,0,stream>>>(h1,f2w,h2);
    k_gnstats<<<256,256,0,stream>>>(h2,st2,16384);
    k12_final<<<4096,256,0,stream>>>(outp,h2,st2,g2g,g2b,(float*)d_out);
}

// Round 4
// 611.232 us; speedup vs baseline: 3.2942x; 3.2942x over previous
//
#include <hip/hip_runtime.h>
#include <hip/hip_bf16.h>
#include <math.h>

#define L4K 4096

// ---------------- K1: pre-LN + bott_in + in_proj ----------------
__global__ __launch_bounds__(256) void k1_pre(
    const float* __restrict__ x, const float* __restrict__ png, const float* __restrict__ pnb,
    const float* __restrict__ biw, const float* __restrict__ bib, const float* __restrict__ ipw,
    float* __restrict__ zc, float* __restrict__ xcp, float* __restrict__ zg)
{
    __shared__ float xs[128*32];   // [c][i], 32 tokens
    __shared__ float wl[64*128];   // bott_in_w [j][c]
    __shared__ float zs[32*65];    // z per token (padded)
    __shared__ float ipl[64*16];   // in_proj_w
    __shared__ float pngs[128], pnbs[128];
    int tid = threadIdx.x;
    int l0 = blockIdx.x*32, b = blockIdx.y;
    const float* xb = x + (size_t)b*128*L4K;
    for (int it = 0; it < 16; ++it) {
        int f = it*256 + tid; int c = f>>5, i = f&31;
        xs[f] = xb[(size_t)c*L4K + l0 + i];
    }
    for (int f = tid; f < 8192; f += 256) wl[f] = biw[f];
    for (int f = tid; f < 1024; f += 256) ipl[f] = ipw[f];
    if (tid < 128) { pngs[tid] = png[tid]; pnbs[tid] = pnb[tid]; }
    __syncthreads();
    int i = tid & 31, q = tid >> 5;   // q in 0..7, 8 outputs each
    float s = 0.f, s2 = 0.f;
    for (int c = 0; c < 128; ++c) { float v = xs[c*32+i]; s += v; s2 = fmaf(v,v,s2); }
    float mn = s*(1.f/128.f);
    float rstd = rsqrtf(s2*(1.f/128.f) - mn*mn + 1e-5f);
    float z[8];
    #pragma unroll
    for (int jj = 0; jj < 8; ++jj) z[jj] = bib[q*8+jj];
    for (int c = 0; c < 128; ++c) {
        float xv = (xs[c*32+i] - mn)*rstd*pngs[c] + pnbs[c];
        #pragma unroll
        for (int jj = 0; jj < 8; ++jj) z[jj] = fmaf(xv, wl[(q*8+jj)*128 + c], z[jj]);
    }
    #pragma unroll
    for (int jj = 0; jj < 8; ++jj) zs[i*65 + q*8 + jj] = z[jj];
    __syncthreads();
    if (tid < 128) {
        int i2 = tid & 31, g = tid >> 5;   // g = chunk 0..3
        int n = g*8 + b; int l = l0 + i2;
        float zv[16];
        #pragma unroll
        for (int k = 0; k < 16; ++k) zv[k] = zs[i2*65 + g*16 + k];
        size_t tb = (size_t)n*L4K + l;
        float4* zc4 = (float4*)(zc + tb*16);
        zc4[0] = make_float4(zv[0],zv[1],zv[2],zv[3]);
        zc4[1] = make_float4(zv[4],zv[5],zv[6],zv[7]);
        zc4[2] = make_float4(zv[8],zv[9],zv[10],zv[11]);
        zc4[3] = make_float4(zv[12],zv[13],zv[14],zv[15]);
        float* xo = xcp + tb*32;
        float* zo = zg + tb*32;
        #pragma unroll
        for (int o = 0; o < 64; ++o) {
            float a = 0.f;
            #pragma unroll
            for (int k = 0; k < 16; ++k) a = fmaf(zv[k], ipl[o*16+k], a);
            if (o < 32) xo[o] = a; else zo[o-32] = a;
        }
    }
}

// ---------------- K2: conv + silu + x_proj + dt + scan records ----------------
__global__ __launch_bounds__(128) void k2_conv(
    const float* __restrict__ xcp, const float* __restrict__ cw, const float* __restrict__ cb,
    const float* __restrict__ xpw, const float* __restrict__ dtw, const float* __restrict__ dtb,
    float* __restrict__ S)
{
    __shared__ float xt[131*33];
    __shared__ float cwl[128], cbl[32], xpl[33*32], dtwl[32], dtbl[32];
    int tid = threadIdx.x;
    int t0 = blockIdx.x*128; int n = blockIdx.y;
    const float* xb = xcp + (size_t)n*L4K*32;
    for (int f = tid; f < 131*32; f += 128) {
        int r = f >> 5, d = f & 31;
        int t = t0 - 3 + r;
        xt[r*33 + d] = (t >= 0) ? xb[(size_t)t*32 + d] : 0.f;
    }
    if (tid < 128) cwl[tid] = cw[tid];
    if (tid < 32) { cbl[tid] = cb[tid]; dtwl[tid] = dtw[tid]; dtbl[tid] = dtb[tid]; }
    for (int f = tid; f < 33*32; f += 128) xpl[f] = xpw[f];
    __syncthreads();
    int t = t0 + tid;
    float xc[32];
    #pragma unroll
    for (int d = 0; d < 32; ++d) {
        float sv = cbl[d];
        #pragma unroll
        for (int k = 0; k < 4; ++k) sv = fmaf(cwl[d*4+k], xt[(tid+k)*33 + d], sv);
        xc[d] = sv / (1.f + __expf(-sv));   // silu
    }
    float dtr = 0.f; float Bv[16], Cv[16];
    #pragma unroll
    for (int dd = 0; dd < 32; ++dd) dtr = fmaf(xc[dd], xpl[dd], dtr);
    #pragma unroll
    for (int o = 0; o < 16; ++o) {
        float a = 0.f, a2 = 0.f;
        #pragma unroll
        for (int dd = 0; dd < 32; ++dd) {
            a  = fmaf(xc[dd], xpl[(1+o)*32+dd],  a);
            a2 = fmaf(xc[dd], xpl[(17+o)*32+dd], a2);
        }
        Bv[o] = a; Cv[o] = a2;
    }
    float* r = S + ((size_t)n*L4K + t)*128;
    #pragma unroll
    for (int d = 0; d < 32; ++d) {
        float dv = fmaf(dtr, dtwl[d], dtbl[d]);
        float sp = fmaxf(dv, 0.f) + log1pf(__expf(-fabsf(dv)));  // softplus
        r[d]      = sp;
        r[32 + d] = sp * xc[d];
        r[96 + d] = xc[d];
    }
    #pragma unroll
    for (int o = 0; o < 16; ++o) { r[64+o] = Bv[o]; r[80+o] = Cv[o]; }
}

// ---------------- K3a: chunk-local scan -> (prodA, h_end) per (n,d,s,chunk) ----
// 16 chunks of 256 steps. block = (chunk, n), 512 threads = 32 d x 16 s.
__global__ __launch_bounds__(512) void k3a_local(
    const float* __restrict__ S, const float* __restrict__ alog,
    float* __restrict__ chunkA, float* __restrict__ chunkH)
{
    int tid = threadIdx.x;
    int d = tid >> 4, s = tid & 15;
    int chunk = blockIdx.x, n = blockIdx.y;
    float A = -__expf(alog[d*16 + s]);
    const float* Sp = S + ((size_t)n*L4K + chunk*256)*128;
    float h = 0.f, ap = 1.f;
    #pragma unroll 4
    for (int t = 0; t < 256; ++t) {
        const float* r = Sp + (size_t)t*128;
        float dtv = r[d], dxv = r[32+d], Bvv = r[64+s];
        float dA = __expf(dtv * A);
        h = fmaf(dA, h, dxv * Bvv);
        ap *= dA;
    }
    size_t idx = (((size_t)n*32 + d)*16 + s)*16 + chunk;
    chunkA[idx] = ap;
    chunkH[idx] = h;
}

// ---------------- K3b: prefix across chunks per (n,d,s) ----------------
__global__ __launch_bounds__(256) void k3b_prefix(
    const float* __restrict__ chunkA, const float* __restrict__ chunkH,
    float* __restrict__ hstart)
{
    int nds = blockIdx.x*256 + threadIdx.x;   // 0..16383
    const float* ca = chunkA + (size_t)nds*16;
    const float* ch = chunkH + (size_t)nds*16;
    float* hs = hstart + (size_t)nds*16;
    float h = 0.f;
    hs[0] = 0.f;
    #pragma unroll
    for (int c = 0; c < 15; ++c) {
        h = fmaf(h, ca[c], ch[c]);
        hs[c+1] = h;
    }
}

// ---------------- K3c: recompute with start state, emit y ----------------
__global__ __launch_bounds__(512) void k3c_emit(
    const float* __restrict__ S, const float* __restrict__ alog,
    const float* __restrict__ hstart, float* __restrict__ y)
{
    __shared__ float ys[256*32];
    int tid = threadIdx.x;
    int d = tid >> 4, s = tid & 15;
    int chunk = blockIdx.x, n = blockIdx.y;
    float A = -__expf(alog[d*16 + s]);
    const float* Sp = S + ((size_t)n*L4K + chunk*256)*128;
    float h = hstart[(((size_t)n*32 + d)*16 + s)*16 + chunk];
    #pragma unroll 2
    for (int t = 0; t < 256; ++t) {
        const float* r = Sp + (size_t)t*128;
        float dtv = r[d], dxv = r[32+d], Bvv = r[64+s], Cvv = r[80+s];
        float dA = __expf(dtv * A);
        h = fmaf(dA, h, dxv * Bvv);
        float p = h * Cvv;
        p += __shfl_xor(p, 8, 16);
        p += __shfl_xor(p, 4, 16);
        p += __shfl_xor(p, 2, 16);
        p += __shfl_xor(p, 1, 16);
        if (s == 0) ys[t*32 + d] = p;
    }
    __syncthreads();
    float4* yb = (float4*)(y + ((size_t)n*L4K + chunk*256)*32);
    const float4* ysv = (const float4*)ys;
    #pragma unroll
    for (int i = 0; i < 4; ++i) yb[tid + i*512] = ysv[tid + i*512];
}

// ---------------- K5: gate + out_proj + residual -> m ----------------
__global__ __launch_bounds__(256) void k5_out(
    const float* __restrict__ y, const float* __restrict__ S, const float* __restrict__ zg,
    const float* __restrict__ zc, const float* __restrict__ Dp, const float* __restrict__ opw,
    float* __restrict__ m)
{
    int id = blockIdx.x*256 + threadIdx.x;  // 0..131071  (n,t)
    int n = id >> 12, t = id & 4095;
    const float* yp  = y  + (size_t)id*32;
    const float* xcr = S  + (size_t)id*128 + 96;
    const float* zgp = zg + (size_t)id*32;
    const float* zcp = zc + (size_t)id*16;
    float v[32];
    #pragma unroll
    for (int dd = 0; dd < 32; ++dd) {
        float g = zgp[dd];
        float sig = 1.f/(1.f + __expf(-g));
        v[dd] = (yp[dd] + xcr[dd]*Dp[dd]) * (g*sig);
    }
    int b = n & 7, g4 = n >> 3;
    float* mp = m + ((size_t)b*L4K + t)*64 + g4*16;
    #pragma unroll
    for (int j = 0; j < 16; ++j) {
        float a = zcp[j];
        #pragma unroll
        for (int dd = 0; dd < 32; ++dd) a = fmaf(v[dd], opw[j*32+dd], a);
        mp[j] = a;
    }
}

// ---------------- K6: post-LN + bott_out + out_pre = 2x + token ----------------
__global__ __launch_bounds__(256) void k6_post(
    const float* __restrict__ m, const float* __restrict__ x,
    const float* __restrict__ pog, const float* __restrict__ pob,
    const float* __restrict__ bow, const float* __restrict__ bob,
    const float* __restrict__ rsp, float* __restrict__ outp)
{
    __shared__ float ms[64*65];
    __shared__ float wl[128*64];   // bott_out_w [c][j]
    __shared__ float pogs[64], pobs[64];
    int tid = threadIdx.x;
    int l0 = blockIdx.x*64, b = blockIdx.y;
    const float* mb = m + ((size_t)b*L4K + l0)*64;
    for (int f = tid; f < 4096; f += 256) {
        int i = f>>6, j = f&63;
        ms[i*65 + j] = mb[f];
    }
    for (int f = tid; f < 8192; f += 256) wl[f] = bow[f];
    if (tid < 64) { pogs[tid] = pog[tid]; pobs[tid] = pob[tid]; }
    __syncthreads();
    float rs = rsp[0];
    int i = tid & 63, q = tid >> 6;   // q: 32 channels each
    float s = 0.f, s2 = 0.f;
    for (int j = 0; j < 64; ++j) { float v = ms[i*65+j]; s += v; s2 = fmaf(v,v,s2); }
    float mn = s*(1.f/64.f);
    float rstd = rsqrtf(s2*(1.f/64.f) - mn*mn + 1e-5f);
    float acc[32];
    #pragma unroll
    for (int cc = 0; cc < 32; ++cc) acc[cc] = bob[q*32+cc];
    for (int j = 0; j < 64; ++j) {
        float v = (ms[i*65+j]-mn)*rstd*pogs[j] + pobs[j];
        #pragma unroll
        for (int cc = 0; cc < 32; ++cc) acc[cc] = fmaf(v, wl[(q*32+cc)*64+j], acc[cc]);
    }
    const float* xb = x + (size_t)b*128*L4K + l0 + i;
    float* ob = outp + (size_t)b*128*L4K + l0 + i;
    #pragma unroll
    for (int cc = 0; cc < 32; ++cc) {
        int c = q*32 + cc;
        ob[(size_t)c*L4K] = 2.f*xb[(size_t)c*L4K] + acc[cc]*rs;
    }
}

// ---------------- GEMM helpers ----------------
#define FMA4(acc, sc, v) { acc.x = fmaf(sc, v.x, acc.x); acc.y = fmaf(sc, v.y, acc.y); acc.z = fmaf(sc, v.z, acc.z); acc.w = fmaf(sc, v.w, acc.w); }

// ---------------- K7: fc1 (512x128 @ [128 x 4096]) ----------------
__global__ __launch_bounds__(256) void k7_fc1(
    const float* __restrict__ ap, const float* __restrict__ w, float* __restrict__ h1)
{
    __shared__ float ws_w[64*128];  // [oo][k]
    __shared__ float bs[128*64];    // [k][ll]
    int tid = threadIdx.x;
    int l0 = blockIdx.x*64, o0 = blockIdx.y*64, b = blockIdx.z;
    for (int f = tid; f < 8192; f += 256) {
        int oo = f>>7, k = f&127;
        ws_w[f] = w[(size_t)(o0+oo)*128 + k];
    }
    for (int f = tid; f < 8192; f += 256) {
        int k = f>>6, ll = f&63;
        bs[f] = ap[(size_t)b*128*L4K + (size_t)k*L4K + l0 + ll];
    }
    __syncthreads();
    int tl = tid & 15, to = tid >> 4;
    float4 acc0 = make_float4(0,0,0,0), acc1 = acc0, acc2 = acc0, acc3 = acc0;
    for (int k = 0; k < 128; k += 4) {
        float4 a0 = *(const float4*)&ws_w[(to*4+0)*128 + k];
        float4 a1 = *(const float4*)&ws_w[(to*4+1)*128 + k];
        float4 a2 = *(const float4*)&ws_w[(to*4+2)*128 + k];
        float4 a3 = *(const float4*)&ws_w[(to*4+3)*128 + k];
        float4 v0 = *(const float4*)&bs[(k+0)*64 + tl*4];
        float4 v1 = *(const float4*)&bs[(k+1)*64 + tl*4];
        float4 v2 = *(const float4*)&bs[(k+2)*64 + tl*4];
        float4 v3 = *(const float4*)&bs[(k+3)*64 + tl*4];
        FMA4(acc0, a0.x, v0) FMA4(acc0, a0.y, v1) FMA4(acc0, a0.z, v2) FMA4(acc0, a0.w, v3)
        FMA4(acc1, a1.x, v0) FMA4(acc1, a1.y, v1) FMA4(acc1, a1.z, v2) FMA4(acc1, a1.w, v3)
        FMA4(acc2, a2.x, v0) FMA4(acc2, a2.y, v1) FMA4(acc2, a2.z, v2) FMA4(acc2, a2.w, v3)
        FMA4(acc3, a3.x, v0) FMA4(acc3, a3.y, v1) FMA4(acc3, a3.z, v2) FMA4(acc3, a3.w, v3)
    }
    float* hb = h1 + (size_t)b*512*L4K + (size_t)(o0 + to*4)*L4K + l0 + tl*4;
    *(float4*)&hb[0]        = acc0;
    *(float4*)&hb[L4K]      = acc1;
    *(float4*)&hb[2*L4K]    = acc2;
    *(float4*)&hb[3*L4K]    = acc3;
}

// ---------------- K10: fc2 (128x512 @ [512 x 4096]) ----------------
__global__ __launch_bounds__(256) void k10_fc2(
    const float* __restrict__ h1, const float* __restrict__ w, float* __restrict__ h2)
{
    __shared__ float ws_w[64*128];
    __shared__ float bs[128*64];
    int tid = threadIdx.x;
    int l0 = blockIdx.x*64, o0 = blockIdx.y*64, b = blockIdx.z;
    int tl = tid & 15, to = tid >> 4;
    float4 acc0 = make_float4(0,0,0,0), acc1 = acc0, acc2 = acc0, acc3 = acc0;
    for (int kc = 0; kc < 4; ++kc) {
        if (kc) __syncthreads();
        for (int f = tid; f < 8192; f += 256) {
            int oo = f>>7, k = f&127;
            ws_w[f] = w[(size_t)(o0+oo)*512 + kc*128 + k];
        }
        for (int f = tid; f < 8192; f += 256) {
            int k = f>>6, ll = f&63;
            bs[f] = h1[(size_t)b*512*L4K + (size_t)(kc*128+k)*L4K + l0 + ll];
        }
        __syncthreads();
        for (int k = 0; k < 128; k += 4) {
            float4 a0 = *(const float4*)&ws_w[(to*4+0)*128 + k];
            float4 a1 = *(const float4*)&ws_w[(to*4+1)*128 + k];
            float4 a2 = *(const float4*)&ws_w[(to*4+2)*128 + k];
            float4 a3 = *(const float4*)&ws_w[(to*4+3)*128 + k];
            float4 v0 = *(const float4*)&bs[(k+0)*64 + tl*4];
            float4 v1 = *(const float4*)&bs[(k+1)*64 + tl*4];
            float4 v2 = *(const float4*)&bs[(k+2)*64 + tl*4];
            float4 v3 = *(const float4*)&bs[(k+3)*64 + tl*4];
            FMA4(acc0, a0.x, v0) FMA4(acc0, a0.y, v1) FMA4(acc0, a0.z, v2) FMA4(acc0, a0.w, v3)
            FMA4(acc1, a1.x, v0) FMA4(acc1, a1.y, v1) FMA4(acc1, a1.z, v2) FMA4(acc1, a1.w, v3)
            FMA4(acc2, a2.x, v0) FMA4(acc2, a2.y, v1) FMA4(acc2, a2.z, v2) FMA4(acc2, a2.w, v3)
            FMA4(acc3, a3.x, v0) FMA4(acc3, a3.y, v1) FMA4(acc3, a3.z, v2) FMA4(acc3, a3.w, v3)
        }
    }
    float* hb = h2 + (size_t)b*128*L4K + (size_t)(o0 + to*4)*L4K + l0 + tl*4;
    *(float4*)&hb[0]     = acc0;
    *(float4*)&hb[L4K]   = acc1;
    *(float4*)&hb[2*L4K] = acc2;
    *(float4*)&hb[3*L4K] = acc3;
}

// ---------------- GroupNorm stats (generic) ----------------
__global__ __launch_bounds__(256) void k_gnstats(
    const float* __restrict__ h, float* __restrict__ stats, int per_group)
{
    __shared__ float sred[256], sred2[256];
    int bid = blockIdx.x, tid = threadIdx.x;
    const float4* base = (const float4*)(h + (size_t)bid*per_group);
    int n4 = per_group >> 2;
    float s = 0.f, s2 = 0.f;
    for (int i = tid; i < n4; i += 256) {
        float4 v = base[i];
        s += v.x+v.y+v.z+v.w;
        s2 = fmaf(v.x,v.x,s2); s2 = fmaf(v.y,v.y,s2); s2 = fmaf(v.z,v.z,s2); s2 = fmaf(v.w,v.w,s2);
    }
    sred[tid] = s; sred2[tid] = s2; __syncthreads();
    for (int off = 128; off; off >>= 1) {
        if (tid < off) { sred[tid] += sred[tid+off]; sred2[tid] += sred2[tid+off]; }
        __syncthreads();
    }
    if (tid == 0) {
        float inv = 1.f/(float)per_group;
        float mn = sred[0]*inv;
        float var = sred2[0]*inv - mn*mn;
        stats[bid*2]   = mn;
        stats[bid*2+1] = rsqrtf(var + 1e-5f);
    }
}

// ---------------- K9: gn1 apply + exact gelu (in place on h1) ----------------
__global__ __launch_bounds__(256) void k9_gngelu(
    float* __restrict__ h1, const float* __restrict__ stats,
    const float* __restrict__ g1, const float* __restrict__ b1)
{
    int f = blockIdx.x*256 + threadIdx.x;   // float4 index, total 4194304
    int e = f*4;
    int c = (e >> 12) & 511;
    int b = e >> 21;
    int sg = b*32 + (c >> 4);
    float mn = stats[sg*2], rstd = stats[sg*2+1];
    float gv = g1[c], bv = b1[c];
    float4 v = ((float4*)h1)[f];
    float t0 = (v.x-mn)*rstd*gv + bv;
    float t1 = (v.y-mn)*rstd*gv + bv;
    float t2 = (v.z-mn)*rstd*gv + bv;
    float t3 = (v.w-mn)*rstd*gv + bv;
    v.x = 0.5f*t0*(1.f + erff(t0*0.70710678118654752f));
    v.y = 0.5f*t1*(1.f + erff(t1*0.70710678118654752f));
    v.z = 0.5f*t2*(1.f + erff(t2*0.70710678118654752f));
    v.w = 0.5f*t3*(1.f + erff(t3*0.70710678118654752f));
    ((float4*)h1)[f] = v;
}

// ---------------- K12: final out = out_pre + gn2(h2) ----------------
__global__ __launch_bounds__(256) void k12_final(
    const float* __restrict__ outp, const float* __restrict__ h2,
    const float* __restrict__ stats, const float* __restrict__ g2,
    const float* __restrict__ b2, float* __restrict__ out)
{
    int f = blockIdx.x*256 + threadIdx.x;   // float4 index, total 1048576
    int e = f*4;
    int c = (e >> 12) & 127;
    int b = e >> 19;
    int sg = b*32 + (c >> 2);
    float mn = stats[sg*2], rstd = stats[sg*2+1];
    float gv = g2[c], bv = b2[c];
    float4 o = ((const float4*)outp)[f];
    float4 h = ((const float4*)h2)[f];
    float4 r;
    r.x = o.x + (h.x-mn)*rstd*gv + bv;
    r.y = o.y + (h.y-mn)*rstd*gv + bv;
    r.z = o.z + (h.z-mn)*rstd*gv + bv;
    r.w = o.w + (h.w-mn)*rstd*gv + bv;
    ((float4*)out)[f] = r;
}

extern "C" void kernel_launch(void* const* d_in, const int* in_sizes, int n_in,
                              void* d_out, int out_size, void* d_ws, size_t ws_size,
                              hipStream_t stream) {
    (void)in_sizes; (void)n_in; (void)out_size; (void)ws_size;
    const float* x    = (const float*)d_in[0];
    const float* png  = (const float*)d_in[1];
    const float* pnb  = (const float*)d_in[2];
    const float* biw  = (const float*)d_in[3];
    const float* bib  = (const float*)d_in[4];
    const float* ipw  = (const float*)d_in[5];
    const float* cw   = (const float*)d_in[6];
    const float* cb   = (const float*)d_in[7];
    const float* xpw  = (const float*)d_in[8];
    const float* dtw  = (const float*)d_in[9];
    const float* dtb  = (const float*)d_in[10];
    const float* alog = (const float*)d_in[11];
    const float* Dp   = (const float*)d_in[12];
    const float* opw  = (const float*)d_in[13];
    const float* pog  = (const float*)d_in[14];
    const float* pob  = (const float*)d_in[15];
    const float* bow  = (const float*)d_in[16];
    const float* bob  = (const float*)d_in[17];
    const float* rsp  = (const float*)d_in[18];
    const float* f1w  = (const float*)d_in[19];
    const float* g1g  = (const float*)d_in[20];
    const float* g1b  = (const float*)d_in[21];
    const float* f2w  = (const float*)d_in[22];
    const float* g2g  = (const float*)d_in[23];
    const float* g2b  = (const float*)d_in[24];

    char* ws = (char*)d_ws;
    // Layout (bytes), with aliasing across phases (peak 112 MiB):
    float* S    = (float*)(ws + 0);           // 64 MB  (records, dead after k5)
    float* zc   = (float*)(ws + 67108864);    // 8 MB   (dead after k5)
    float* zg   = (float*)(ws + 75497472);    // 16 MB  (dead after k5)
    float* xcp  = (float*)(ws + 92274688);    // 16 MB  (dead after k2)
    float* y    = (float*)(ws + 92274688);    // reuses xcp (k3 after k2)
    float* m    = (float*)(ws + 109051904);   // 8 MB   (written by k5)
    // scan chunk stats alias into m's region (m not live until k5):
    float* chA  = (float*)(ws + 109051904);          // 1 MB
    float* chH  = (float*)(ws + 109051904 + 1048576);// 1 MB
    float* hst  = (float*)(ws + 109051904 + 2097152);// 1 MB
    float* outp = (float*)(ws + 0);           // 16 MB  (post phase, aliases S)
    float* h1   = (float*)(ws + 16777216);    // 64 MB  (aliases S)
    float* h2   = (float*)(ws + 83886080);    // 16 MB  (aliases zg/y dead regions)
    float* st1  = (float*)(ws + 100663296);
    float* st2  = (float*)(ws + 100728832);

    k1_pre<<<dim3(128,8),256,0,stream>>>(x,png,pnb,biw,bib,ipw,zc,xcp,zg);
    k2_conv<<<dim3(32,32),128,0,stream>>>(xcp,cw,cb,xpw,dtw,dtb,S);
    k3a_local<<<dim3(16,32),512,0,stream>>>(S,alog,chA,chH);
    k3b_prefix<<<64,256,0,stream>>>(chA,chH,hst);
    k3c_emit<<<dim3(16,32),512,0,stream>>>(S,alog,hst,y);
    k5_out<<<512,256,0,stream>>>(y,S,zg,zc,Dp,opw,m);
    k6_post<<<dim3(64,8),256,0,stream>>>(m,x,pog,pob,bow,bob,rsp,outp);
    k7_fc1<<<dim3(64,8,8),256,0,stream>>>(outp,f1w,h1);
    k_gnstats<<<256,256,0,stream>>>(h1,st1,65536);
    k9_gngelu<<<16384,256,0,stream>>>(h1,st1,g1g,g1b);
    k10_fc2<<<dim3(64,2,8),256,0,stream>>>(h1,f2w,h2);
    k_gnstats<<<256,256,0,stream>>>(h2,st2,16384);
    k12_final<<<4096,256,0,stream>>>(outp,h2,st2,g2g,g2b,(float*)d_out);
}

// Round 5
// 570.438 us; speedup vs baseline: 3.5298x; 1.0715x over previous
//
#include <hip/hip_runtime.h>
#include <hip/hip_bf16.h>
#include <math.h>

#define L4K 4096
#define NCH 32     // chunks over L
#define CL  128    // timesteps per chunk
#define TB  32     // timesteps per LDS stage
#define NST (CL/TB)

// ---------------- K1: pre-LN + bott_in + in_proj ----------------
__global__ __launch_bounds__(256) void k1_pre(
    const float* __restrict__ x, const float* __restrict__ png, const float* __restrict__ pnb,
    const float* __restrict__ biw, const float* __restrict__ bib, const float* __restrict__ ipw,
    float* __restrict__ zc, float* __restrict__ xcp, float* __restrict__ zg)
{
    __shared__ float xs[128*32];   // [c][i], 32 tokens
    __shared__ float wl[64*128];   // bott_in_w [j][c]
    __shared__ float zs[32*65];    // z per token (padded)
    __shared__ float ipl[64*16];   // in_proj_w
    __shared__ float pngs[128], pnbs[128];
    int tid = threadIdx.x;
    int l0 = blockIdx.x*32, b = blockIdx.y;
    const float* xb = x + (size_t)b*128*L4K;
    for (int it = 0; it < 16; ++it) {
        int f = it*256 + tid; int c = f>>5, i = f&31;
        xs[f] = xb[(size_t)c*L4K + l0 + i];
    }
    for (int f = tid; f < 8192; f += 256) wl[f] = biw[f];
    for (int f = tid; f < 1024; f += 256) ipl[f] = ipw[f];
    if (tid < 128) { pngs[tid] = png[tid]; pnbs[tid] = pnb[tid]; }
    __syncthreads();
    int i = tid & 31, q = tid >> 5;   // q in 0..7, 8 outputs each
    float s = 0.f, s2 = 0.f;
    for (int c = 0; c < 128; ++c) { float v = xs[c*32+i]; s += v; s2 = fmaf(v,v,s2); }
    float mn = s*(1.f/128.f);
    float rstd = rsqrtf(s2*(1.f/128.f) - mn*mn + 1e-5f);
    float z[8];
    #pragma unroll
    for (int jj = 0; jj < 8; ++jj) z[jj] = bib[q*8+jj];
    for (int c = 0; c < 128; ++c) {
        float xv = (xs[c*32+i] - mn)*rstd*pngs[c] + pnbs[c];
        #pragma unroll
        for (int jj = 0; jj < 8; ++jj) z[jj] = fmaf(xv, wl[(q*8+jj)*128 + c], z[jj]);
    }
    #pragma unroll
    for (int jj = 0; jj < 8; ++jj) zs[i*65 + q*8 + jj] = z[jj];
    __syncthreads();
    if (tid < 128) {
        int i2 = tid & 31, g = tid >> 5;   // g = chunk 0..3
        int n = g*8 + b; int l = l0 + i2;
        float zv[16];
        #pragma unroll
        for (int k = 0; k < 16; ++k) zv[k] = zs[i2*65 + g*16 + k];
        size_t tb = (size_t)n*L4K + l;
        float4* zc4 = (float4*)(zc + tb*16);
        zc4[0] = make_float4(zv[0],zv[1],zv[2],zv[3]);
        zc4[1] = make_float4(zv[4],zv[5],zv[6],zv[7]);
        zc4[2] = make_float4(zv[8],zv[9],zv[10],zv[11]);
        zc4[3] = make_float4(zv[12],zv[13],zv[14],zv[15]);
        float* xo = xcp + tb*32;
        float* zo = zg + tb*32;
        #pragma unroll
        for (int o = 0; o < 64; ++o) {
            float a = 0.f;
            #pragma unroll
            for (int k = 0; k < 16; ++k) a = fmaf(zv[k], ipl[o*16+k], a);
            if (o < 32) xo[o] = a; else zo[o-32] = a;
        }
    }
}

// ---------------- K2: conv + silu + x_proj + dt + scan records ----------------
__global__ __launch_bounds__(128) void k2_conv(
    const float* __restrict__ xcp, const float* __restrict__ cw, const float* __restrict__ cb,
    const float* __restrict__ xpw, const float* __restrict__ dtw, const float* __restrict__ dtb,
    float* __restrict__ S)
{
    __shared__ float xt[131*33];
    __shared__ float cwl[128], cbl[32], xpl[33*32], dtwl[32], dtbl[32];
    int tid = threadIdx.x;
    int t0 = blockIdx.x*128; int n = blockIdx.y;
    const float* xb = xcp + (size_t)n*L4K*32;
    for (int f = tid; f < 131*32; f += 128) {
        int r = f >> 5, d = f & 31;
        int t = t0 - 3 + r;
        xt[r*33 + d] = (t >= 0) ? xb[(size_t)t*32 + d] : 0.f;
    }
    if (tid < 128) cwl[tid] = cw[tid];
    if (tid < 32) { cbl[tid] = cb[tid]; dtwl[tid] = dtw[tid]; dtbl[tid] = dtb[tid]; }
    for (int f = tid; f < 33*32; f += 128) xpl[f] = xpw[f];
    __syncthreads();
    int t = t0 + tid;
    float xc[32];
    #pragma unroll
    for (int d = 0; d < 32; ++d) {
        float sv = cbl[d];
        #pragma unroll
        for (int k = 0; k < 4; ++k) sv = fmaf(cwl[d*4+k], xt[(tid+k)*33 + d], sv);
        xc[d] = sv / (1.f + __expf(-sv));   // silu
    }
    float dtr = 0.f; float Bv[16], Cv[16];
    #pragma unroll
    for (int dd = 0; dd < 32; ++dd) dtr = fmaf(xc[dd], xpl[dd], dtr);
    #pragma unroll
    for (int o = 0; o < 16; ++o) {
        float a = 0.f, a2 = 0.f;
        #pragma unroll
        for (int dd = 0; dd < 32; ++dd) {
            a  = fmaf(xc[dd], xpl[(1+o)*32+dd],  a);
            a2 = fmaf(xc[dd], xpl[(17+o)*32+dd], a2);
        }
        Bv[o] = a; Cv[o] = a2;
    }
    float* r = S + ((size_t)n*L4K + t)*128;
    #pragma unroll
    for (int d = 0; d < 32; ++d) {
        float dv = fmaf(dtr, dtwl[d], dtbl[d]);
        float sp = fmaxf(dv, 0.f) + log1pf(__expf(-fabsf(dv)));  // softplus
        r[d]      = sp;
        r[32 + d] = sp * xc[d];
        r[96 + d] = xc[d];
    }
    #pragma unroll
    for (int o = 0; o < 16; ++o) { r[64+o] = Bv[o]; r[80+o] = Cv[o]; }
}

// ---------------- K3a: chunk-local scan -> (prodA, h_end) ----------------
// block = (chunk, n), 512 threads = 32 d x 16 s. LDS-staged, double-buffered.
__global__ __launch_bounds__(512) void k3a_local(
    const float* __restrict__ S, const float* __restrict__ alog,
    float* __restrict__ chunkA, float* __restrict__ chunkH)
{
    __shared__ float sb[2][TB*128];
    int tid = threadIdx.x;
    int d = tid >> 4, s = tid & 15;
    int chunk = blockIdx.x, n = blockIdx.y;
    float A = -__expf(alog[d*16 + s]);
    const float4* Sg = (const float4*)(S + ((size_t)n*L4K + (size_t)chunk*CL)*128);
    float4 p0 = Sg[tid], p1 = Sg[tid + 512];
    ((float4*)sb[0])[tid] = p0; ((float4*)sb[0])[tid+512] = p1;
    __syncthreads();
    float h = 0.f, ap = 1.f;
    for (int st = 0; st < NST; ++st) {
        int cur = st & 1;
        float4 q0, q1;
        if (st+1 < NST) {
            const float4* Sn = Sg + (size_t)(st+1)*TB*32;
            q0 = Sn[tid]; q1 = Sn[tid+512];
        }
        const float* sc = sb[cur];
        #pragma unroll
        for (int tl = 0; tl < TB; ++tl) {
            float dtv = sc[tl*128 + d];
            float dxv = sc[tl*128 + 32 + d];
            float Bvv = sc[tl*128 + 64 + s];
            float dA = __expf(dtv * A);
            h = fmaf(dA, h, dxv * Bvv);
            ap *= dA;
        }
        if (st+1 < NST) {
            ((float4*)sb[cur^1])[tid] = q0;
            ((float4*)sb[cur^1])[tid+512] = q1;
            __syncthreads();
        }
    }
    // layout [chunk][nds]: coalesced write (nds = n*512 + tid)
    chunkA[(size_t)chunk*16384 + n*512 + tid] = ap;
    chunkH[(size_t)chunk*16384 + n*512 + tid] = h;
}

// ---------------- K3b: prefix across chunks per (n,d,s) ----------------
__global__ __launch_bounds__(256) void k3b_prefix(
    const float* __restrict__ chunkA, const float* __restrict__ chunkH,
    float* __restrict__ hstart)
{
    int nds = blockIdx.x*256 + threadIdx.x;   // 0..16383
    float h = 0.f;
    hstart[nds] = 0.f;
    for (int c = 0; c < NCH-1; ++c) {
        h = fmaf(h, chunkA[(size_t)c*16384 + nds], chunkH[(size_t)c*16384 + nds]);
        hstart[(size_t)(c+1)*16384 + nds] = h;
    }
}

// ---------------- K3c: recompute with start state, emit y ----------------
__global__ __launch_bounds__(512) void k3c_emit(
    const float* __restrict__ S, const float* __restrict__ alog,
    const float* __restrict__ hstart, float* __restrict__ y)
{
    __shared__ float sb[2][TB*128];
    __shared__ float ys[TB*32];
    int tid = threadIdx.x;
    int d = tid >> 4, s = tid & 15;
    int chunk = blockIdx.x, n = blockIdx.y;
    float A = -__expf(alog[d*16 + s]);
    const float4* Sg = (const float4*)(S + ((size_t)n*L4K + (size_t)chunk*CL)*128);
    float4* yg = (float4*)(y + ((size_t)n*L4K + (size_t)chunk*CL)*32);
    float4 p0 = Sg[tid], p1 = Sg[tid + 512];
    ((float4*)sb[0])[tid] = p0; ((float4*)sb[0])[tid+512] = p1;
    float h = hstart[(size_t)chunk*16384 + n*512 + tid];
    __syncthreads();
    for (int st = 0; st < NST; ++st) {
        int cur = st & 1;
        float4 q0, q1;
        if (st+1 < NST) {
            const float4* Sn = Sg + (size_t)(st+1)*TB*32;
            q0 = Sn[tid]; q1 = Sn[tid+512];
        }
        const float* sc = sb[cur];
        #pragma unroll
        for (int tl = 0; tl < TB; ++tl) {
            float dtv = sc[tl*128 + d];
            float dxv = sc[tl*128 + 32 + d];
            float Bvv = sc[tl*128 + 64 + s];
            float Cvv = sc[tl*128 + 80 + s];
            float dA = __expf(dtv * A);
            h = fmaf(dA, h, dxv * Bvv);
            float p = h * Cvv;
            p += __shfl_xor(p, 8, 16);
            p += __shfl_xor(p, 4, 16);
            p += __shfl_xor(p, 2, 16);
            p += __shfl_xor(p, 1, 16);
            if (s == 0) ys[tl*32 + d] = p;
        }
        if (st+1 < NST) {
            ((float4*)sb[cur^1])[tid] = q0;
            ((float4*)sb[cur^1])[tid+512] = q1;
        }
        __syncthreads();
        if (tid < TB*8) yg[(size_t)st*TB*8 + tid] = ((const float4*)ys)[tid];
        __syncthreads();   // ys reused next stage
    }
}

// ---------------- K5: gate + out_proj + residual -> m ----------------
__global__ __launch_bounds__(256) void k5_out(
    const float* __restrict__ y, const float* __restrict__ S, const float* __restrict__ zg,
    const float* __restrict__ zc, const float* __restrict__ Dp, const float* __restrict__ opw,
    float* __restrict__ m)
{
    int id = blockIdx.x*256 + threadIdx.x;  // 0..131071  (n,t)
    int n = id >> 12, t = id & 4095;
    const float* yp  = y  + (size_t)id*32;
    const float* xcr = S  + (size_t)id*128 + 96;
    const float* zgp = zg + (size_t)id*32;
    const float* zcp = zc + (size_t)id*16;
    float v[32];
    #pragma unroll
    for (int dd = 0; dd < 32; ++dd) {
        float g = zgp[dd];
        float sig = 1.f/(1.f + __expf(-g));
        v[dd] = (yp[dd] + xcr[dd]*Dp[dd]) * (g*sig);
    }
    int b = n & 7, g4 = n >> 3;
    float* mp = m + ((size_t)b*L4K + t)*64 + g4*16;
    #pragma unroll
    for (int j = 0; j < 16; ++j) {
        float a = zcp[j];
        #pragma unroll
        for (int dd = 0; dd < 32; ++dd) a = fmaf(v[dd], opw[j*32+dd], a);
        mp[j] = a;
    }
}

// ---------------- K6: post-LN + bott_out + out_pre = 2x + token ----------------
__global__ __launch_bounds__(256) void k6_post(
    const float* __restrict__ m, const float* __restrict__ x,
    const float* __restrict__ pog, const float* __restrict__ pob,
    const float* __restrict__ bow, const float* __restrict__ bob,
    const float* __restrict__ rsp, float* __restrict__ outp)
{
    __shared__ float ms[64*65];
    __shared__ float wl[128*64];   // bott_out_w [c][j]
    __shared__ float pogs[64], pobs[64];
    int tid = threadIdx.x;
    int l0 = blockIdx.x*64, b = blockIdx.y;
    const float* mb = m + ((size_t)b*L4K + l0)*64;
    for (int f = tid; f < 4096; f += 256) {
        int i = f>>6, j = f&63;
        ms[i*65 + j] = mb[f];
    }
    for (int f = tid; f < 8192; f += 256) wl[f] = bow[f];
    if (tid < 64) { pogs[tid] = pog[tid]; pobs[tid] = pob[tid]; }
    __syncthreads();
    float rs = rsp[0];
    int i = tid & 63, q = tid >> 6;   // q: 32 channels each
    float s = 0.f, s2 = 0.f;
    for (int j = 0; j < 64; ++j) { float v = ms[i*65+j]; s += v; s2 = fmaf(v,v,s2); }
    float mn = s*(1.f/64.f);
    float rstd = rsqrtf(s2*(1.f/64.f) - mn*mn + 1e-5f);
    float acc[32];
    #pragma unroll
    for (int cc = 0; cc < 32; ++cc) acc[cc] = bob[q*32+cc];
    for (int j = 0; j < 64; ++j) {
        float v = (ms[i*65+j]-mn)*rstd*pogs[j] + pobs[j];
        #pragma unroll
        for (int cc = 0; cc < 32; ++cc) acc[cc] = fmaf(v, wl[(q*32+cc)*64+j], acc[cc]);
    }
    const float* xb = x + (size_t)b*128*L4K + l0 + i;
    float* ob = outp + (size_t)b*128*L4K + l0 + i;
    #pragma unroll
    for (int cc = 0; cc < 32; ++cc) {
        int c = q*32 + cc;
        ob[(size_t)c*L4K] = 2.f*xb[(size_t)c*L4K] + acc[cc]*rs;
    }
}

// ---------------- GEMM helpers ----------------
#define FMA4(acc, sc, v) { acc.x = fmaf(sc, v.x, acc.x); acc.y = fmaf(sc, v.y, acc.y); acc.z = fmaf(sc, v.z, acc.z); acc.w = fmaf(sc, v.w, acc.w); }

// ---------------- K7: fc1 (512x128 @ [128 x 4096]) ----------------
__global__ __launch_bounds__(256) void k7_fc1(
    const float* __restrict__ ap, const float* __restrict__ w, float* __restrict__ h1)
{
    __shared__ float ws_w[64*128];  // [oo][k]
    __shared__ float bs[128*64];    // [k][ll]
    int tid = threadIdx.x;
    int l0 = blockIdx.x*64, o0 = blockIdx.y*64, b = blockIdx.z;
    for (int f = tid; f < 8192; f += 256) {
        int oo = f>>7, k = f&127;
        ws_w[f] = w[(size_t)(o0+oo)*128 + k];
    }
    for (int f = tid; f < 8192; f += 256) {
        int k = f>>6, ll = f&63;
        bs[f] = ap[(size_t)b*128*L4K + (size_t)k*L4K + l0 + ll];
    }
    __syncthreads();
    int tl = tid & 15, to = tid >> 4;
    float4 acc0 = make_float4(0,0,0,0), acc1 = acc0, acc2 = acc0, acc3 = acc0;
    for (int k = 0; k < 128; k += 4) {
        float4 a0 = *(const float4*)&ws_w[(to*4+0)*128 + k];
        float4 a1 = *(const float4*)&ws_w[(to*4+1)*128 + k];
        float4 a2 = *(const float4*)&ws_w[(to*4+2)*128 + k];
        float4 a3 = *(const float4*)&ws_w[(to*4+3)*128 + k];
        float4 v0 = *(const float4*)&bs[(k+0)*64 + tl*4];
        float4 v1 = *(const float4*)&bs[(k+1)*64 + tl*4];
        float4 v2 = *(const float4*)&bs[(k+2)*64 + tl*4];
        float4 v3 = *(const float4*)&bs[(k+3)*64 + tl*4];
        FMA4(acc0, a0.x, v0) FMA4(acc0, a0.y, v1) FMA4(acc0, a0.z, v2) FMA4(acc0, a0.w, v3)
        FMA4(acc1, a1.x, v0) FMA4(acc1, a1.y, v1) FMA4(acc1, a1.z, v2) FMA4(acc1, a1.w, v3)
        FMA4(acc2, a2.x, v0) FMA4(acc2, a2.y, v1) FMA4(acc2, a2.z, v2) FMA4(acc2, a2.w, v3)
        FMA4(acc3, a3.x, v0) FMA4(acc3, a3.y, v1) FMA4(acc3, a3.z, v2) FMA4(acc3, a3.w, v3)
    }
    float* hb = h1 + (size_t)b*512*L4K + (size_t)(o0 + to*4)*L4K + l0 + tl*4;
    *(float4*)&hb[0]        = acc0;
    *(float4*)&hb[L4K]      = acc1;
    *(float4*)&hb[2*L4K]    = acc2;
    *(float4*)&hb[3*L4K]    = acc3;
}

// ---------------- K10: fc2 (128x512 @ [512 x 4096]) ----------------
__global__ __launch_bounds__(256) void k10_fc2(
    const float* __restrict__ h1, const float* __restrict__ w, float* __restrict__ h2)
{
    __shared__ float ws_w[64*128];
    __shared__ float bs[128*64];
    int tid = threadIdx.x;
    int l0 = blockIdx.x*64, o0 = blockIdx.y*64, b = blockIdx.z;
    int tl = tid & 15, to = tid >> 4;
    float4 acc0 = make_float4(0,0,0,0), acc1 = acc0, acc2 = acc0, acc3 = acc0;
    for (int kc = 0; kc < 4; ++kc) {
        if (kc) __syncthreads();
        for (int f = tid; f < 8192; f += 256) {
            int oo = f>>7, k = f&127;
            ws_w[f] = w[(size_t)(o0+oo)*512 + kc*128 + k];
        }
        for (int f = tid; f < 8192; f += 256) {
            int k = f>>6, ll = f&63;
            bs[f] = h1[(size_t)b*512*L4K + (size_t)(kc*128+k)*L4K + l0 + ll];
        }
        __syncthreads();
        for (int k = 0; k < 128; k += 4) {
            float4 a0 = *(const float4*)&ws_w[(to*4+0)*128 + k];
            float4 a1 = *(const float4*)&ws_w[(to*4+1)*128 + k];
            float4 a2 = *(const float4*)&ws_w[(to*4+2)*128 + k];
            float4 a3 = *(const float4*)&ws_w[(to*4+3)*128 + k];
            float4 v0 = *(const float4*)&bs[(k+0)*64 + tl*4];
            float4 v1 = *(const float4*)&bs[(k+1)*64 + tl*4];
            float4 v2 = *(const float4*)&bs[(k+2)*64 + tl*4];
            float4 v3 = *(const float4*)&bs[(k+3)*64 + tl*4];
            FMA4(acc0, a0.x, v0) FMA4(acc0, a0.y, v1) FMA4(acc0, a0.z, v2) FMA4(acc0, a0.w, v3)
            FMA4(acc1, a1.x, v0) FMA4(acc1, a1.y, v1) FMA4(acc1, a1.z, v2) FMA4(acc1, a1.w, v3)
            FMA4(acc2, a2.x, v0) FMA4(acc2, a2.y, v1) FMA4(acc2, a2.z, v2) FMA4(acc2, a2.w, v3)
            FMA4(acc3, a3.x, v0) FMA4(acc3, a3.y, v1) FMA4(acc3, a3.z, v2) FMA4(acc3, a3.w, v3)
        }
    }
    float* hb = h2 + (size_t)b*128*L4K + (size_t)(o0 + to*4)*L4K + l0 + tl*4;
    *(float4*)&hb[0]     = acc0;
    *(float4*)&hb[L4K]   = acc1;
    *(float4*)&hb[2*L4K] = acc2;
    *(float4*)&hb[3*L4K] = acc3;
}

// ---------------- GroupNorm stats (generic) ----------------
__global__ __launch_bounds__(256) void k_gnstats(
    const float* __restrict__ h, float* __restrict__ stats, int per_group)
{
    __shared__ float sred[256], sred2[256];
    int bid = blockIdx.x, tid = threadIdx.x;
    const float4* base = (const float4*)(h + (size_t)bid*per_group);
    int n4 = per_group >> 2;
    float s = 0.f, s2 = 0.f;
    for (int i = tid; i < n4; i += 256) {
        float4 v = base[i];
        s += v.x+v.y+v.z+v.w;
        s2 = fmaf(v.x,v.x,s2); s2 = fmaf(v.y,v.y,s2); s2 = fmaf(v.z,v.z,s2); s2 = fmaf(v.w,v.w,s2);
    }
    sred[tid] = s; sred2[tid] = s2; __syncthreads();
    for (int off = 128; off; off >>= 1) {
        if (tid < off) { sred[tid] += sred[tid+off]; sred2[tid] += sred2[tid+off]; }
        __syncthreads();
    }
    if (tid == 0) {
        float inv = 1.f/(float)per_group;
        float mn = sred[0]*inv;
        float var = sred2[0]*inv - mn*mn;
        stats[bid*2]   = mn;
        stats[bid*2+1] = rsqrtf(var + 1e-5f);
    }
}

// ---------------- K9: gn1 apply + exact gelu (in place on h1) ----------------
__global__ __launch_bounds__(256) void k9_gngelu(
    float* __restrict__ h1, const float* __restrict__ stats,
    const float* __restrict__ g1, const float* __restrict__ b1)
{
    int f = blockIdx.x*256 + threadIdx.x;   // float4 index, total 4194304
    int e = f*4;
    int c = (e >> 12) & 511;
    int b = e >> 21;
    int sg = b*32 + (c >> 4);
    float mn = stats[sg*2], rstd = stats[sg*2+1];
    float gv = g1[c], bv = b1[c];
    float4 v = ((float4*)h1)[f];
    float t0 = (v.x-mn)*rstd*gv + bv;
    float t1 = (v.y-mn)*rstd*gv + bv;
    float t2 = (v.z-mn)*rstd*gv + bv;
    float t3 = (v.w-mn)*rstd*gv + bv;
    v.x = 0.5f*t0*(1.f + erff(t0*0.70710678118654752f));
    v.y = 0.5f*t1*(1.f + erff(t1*0.70710678118654752f));
    v.z = 0.5f*t2*(1.f + erff(t2*0.70710678118654752f));
    v.w = 0.5f*t3*(1.f + erff(t3*0.70710678118654752f));
    ((float4*)h1)[f] = v;
}

// ---------------- K12: final out = out_pre + gn2(h2) ----------------
__global__ __launch_bounds__(256) void k12_final(
    const float* __restrict__ outp, const float* __restrict__ h2,
    const float* __restrict__ stats, const float* __restrict__ g2,
    const float* __restrict__ b2, float* __restrict__ out)
{
    int f = blockIdx.x*256 + threadIdx.x;   // float4 index, total 1048576
    int e = f*4;
    int c = (e >> 12) & 127;
    int b = e >> 19;
    int sg = b*32 + (c >> 2);
    float mn = stats[sg*2], rstd = stats[sg*2+1];
    float gv = g2[c], bv = b2[c];
    float4 o = ((const float4*)outp)[f];
    float4 h = ((const float4*)h2)[f];
    float4 r;
    r.x = o.x + (h.x-mn)*rstd*gv + bv;
    r.y = o.y + (h.y-mn)*rstd*gv + bv;
    r.z = o.z + (h.z-mn)*rstd*gv + bv;
    r.w = o.w + (h.w-mn)*rstd*gv + bv;
    ((float4*)out)[f] = r;
}

extern "C" void kernel_launch(void* const* d_in, const int* in_sizes, int n_in,
                              void* d_out, int out_size, void* d_ws, size_t ws_size,
                              hipStream_t stream) {
    (void)in_sizes; (void)n_in; (void)out_size; (void)ws_size;
    const float* x    = (const float*)d_in[0];
    const float* png  = (const float*)d_in[1];
    const float* pnb  = (const float*)d_in[2];
    const float* biw  = (const float*)d_in[3];
    const float* bib  = (const float*)d_in[4];
    const float* ipw  = (const float*)d_in[5];
    const float* cw   = (const float*)d_in[6];
    const float* cb   = (const float*)d_in[7];
    const float* xpw  = (const float*)d_in[8];
    const float* dtw  = (const float*)d_in[9];
    const float* dtb  = (const float*)d_in[10];
    const float* alog = (const float*)d_in[11];
    const float* Dp   = (const float*)d_in[12];
    const float* opw  = (const float*)d_in[13];
    const float* pog  = (const float*)d_in[14];
    const float* pob  = (const float*)d_in[15];
    const float* bow  = (const float*)d_in[16];
    const float* bob  = (const float*)d_in[17];
    const float* rsp  = (const float*)d_in[18];
    const float* f1w  = (const float*)d_in[19];
    const float* g1g  = (const float*)d_in[20];
    const float* g1b  = (const float*)d_in[21];
    const float* f2w  = (const float*)d_in[22];
    const float* g2g  = (const float*)d_in[23];
    const float* g2b  = (const float*)d_in[24];

    char* ws = (char*)d_ws;
    // Layout (bytes), with aliasing across phases (peak 112 MiB + 6 MB stats):
    float* S    = (float*)(ws + 0);           // 64 MB  (records, dead after k5)
    float* zc   = (float*)(ws + 67108864);    // 8 MB   (dead after k5)
    float* zg   = (float*)(ws + 75497472);    // 16 MB  (dead after k5)
    float* xcp  = (float*)(ws + 92274688);    // 16 MB  (dead after k2)
    float* y    = (float*)(ws + 92274688);    // reuses xcp (k3 after k2)
    float* m    = (float*)(ws + 109051904);   // 8 MB   (written by k5)
    // scan chunk stats alias into m's region (m not live until k5): 3 x 2 MB
    float* chA  = (float*)(ws + 109051904);
    float* chH  = (float*)(ws + 109051904 + 2097152);
    float* hst  = (float*)(ws + 109051904 + 4194304);
    float* outp = (float*)(ws + 0);           // 16 MB  (post phase, aliases S)
    float* h1   = (float*)(ws + 16777216);    // 64 MB  (aliases S)
    float* h2   = (float*)(ws + 83886080);    // 16 MB  (aliases zg/y dead regions)
    float* st1  = (float*)(ws + 100663296);
    float* st2  = (float*)(ws + 100728832);

    k1_pre<<<dim3(128,8),256,0,stream>>>(x,png,pnb,biw,bib,ipw,zc,xcp,zg);
    k2_conv<<<dim3(32,32),128,0,stream>>>(xcp,cw,cb,xpw,dtw,dtb,S);
    k3a_local<<<dim3(NCH,32),512,0,stream>>>(S,alog,chA,chH);
    k3b_prefix<<<64,256,0,stream>>>(chA,chH,hst);
    k3c_emit<<<dim3(NCH,32),512,0,stream>>>(S,alog,hst,y);
    k5_out<<<512,256,0,stream>>>(y,S,zg,zc,Dp,opw,m);
    k6_post<<<dim3(64,8),256,0,stream>>>(m,x,pog,pob,bow,bob,rsp,outp);
    k7_fc1<<<dim3(64,8,8),256,0,stream>>>(outp,f1w,h1);
    k_gnstats<<<256,256,0,stream>>>(h1,st1,65536);
    k9_gngelu<<<16384,256,0,stream>>>(h1,st1,g1g,g1b);
    k10_fc2<<<dim3(64,2,8),256,0,stream>>>(h1,f2w,h2);
    k_gnstats<<<256,256,0,stream>>>(h2,st2,16384);
    k12_final<<<4096,256,0,stream>>>(outp,h2,st2,g2g,g2b,(float*)d_out);
}

// Round 6
// 476.509 us; speedup vs baseline: 4.2256x; 1.1971x over previous
//
#include <hip/hip_runtime.h>
#include <hip/hip_bf16.h>
#include <math.h>

#define L4K 4096
#define NCH 32     // scan chunks over L
#define CL  128    // timesteps per chunk
#define TB  32     // timesteps per LDS stage
#define NST (CL/TB)

typedef __attribute__((ext_vector_type(8))) short short8;
typedef __attribute__((ext_vector_type(4))) float f32x4;

__device__ __forceinline__ unsigned short f2b(float f) {
    unsigned int u = __float_as_uint(f);
    unsigned int r = u + 0x7FFFu + ((u >> 16) & 1u);
    return (unsigned short)(r >> 16);
}
__device__ __forceinline__ float b2f(unsigned short h) {
    return __uint_as_float(((unsigned int)h) << 16);
}

// ---------------- K1: pre-LN + bott_in + in_proj ----------------
__global__ __launch_bounds__(256) void k1_pre(
    const float* __restrict__ x, const float* __restrict__ png, const float* __restrict__ pnb,
    const float* __restrict__ biw, const float* __restrict__ bib, const float* __restrict__ ipw,
    float* __restrict__ zc, float* __restrict__ xcp, float* __restrict__ zg)
{
    __shared__ float xs[128*32];
    __shared__ float wl[64*128];
    __shared__ float zs[32*65];
    __shared__ float ipl[64*16];
    __shared__ float pngs[128], pnbs[128];
    int tid = threadIdx.x;
    int l0 = blockIdx.x*32, b = blockIdx.y;
    const float* xb = x + (size_t)b*128*L4K;
    for (int it = 0; it < 16; ++it) {
        int f = it*256 + tid; int c = f>>5, i = f&31;
        xs[f] = xb[(size_t)c*L4K + l0 + i];
    }
    for (int f = tid; f < 8192; f += 256) wl[f] = biw[f];
    for (int f = tid; f < 1024; f += 256) ipl[f] = ipw[f];
    if (tid < 128) { pngs[tid] = png[tid]; pnbs[tid] = pnb[tid]; }
    __syncthreads();
    int i = tid & 31, q = tid >> 5;
    float s = 0.f, s2 = 0.f;
    for (int c = 0; c < 128; ++c) { float v = xs[c*32+i]; s += v; s2 = fmaf(v,v,s2); }
    float mn = s*(1.f/128.f);
    float rstd = rsqrtf(s2*(1.f/128.f) - mn*mn + 1e-5f);
    float z[8];
    #pragma unroll
    for (int jj = 0; jj < 8; ++jj) z[jj] = bib[q*8+jj];
    for (int c = 0; c < 128; ++c) {
        float xv = (xs[c*32+i] - mn)*rstd*pngs[c] + pnbs[c];
        #pragma unroll
        for (int jj = 0; jj < 8; ++jj) z[jj] = fmaf(xv, wl[(q*8+jj)*128 + c], z[jj]);
    }
    #pragma unroll
    for (int jj = 0; jj < 8; ++jj) zs[i*65 + q*8 + jj] = z[jj];
    __syncthreads();
    if (tid < 128) {
        int i2 = tid & 31, g = tid >> 5;
        int n = g*8 + b; int l = l0 + i2;
        float zv[16];
        #pragma unroll
        for (int k = 0; k < 16; ++k) zv[k] = zs[i2*65 + g*16 + k];
        size_t tb = (size_t)n*L4K + l;
        float4* zc4 = (float4*)(zc + tb*16);
        zc4[0] = make_float4(zv[0],zv[1],zv[2],zv[3]);
        zc4[1] = make_float4(zv[4],zv[5],zv[6],zv[7]);
        zc4[2] = make_float4(zv[8],zv[9],zv[10],zv[11]);
        zc4[3] = make_float4(zv[12],zv[13],zv[14],zv[15]);
        float* xo = xcp + tb*32;
        float* zo = zg + tb*32;
        #pragma unroll
        for (int o = 0; o < 64; ++o) {
            float a = 0.f;
            #pragma unroll
            for (int k = 0; k < 16; ++k) a = fmaf(zv[k], ipl[o*16+k], a);
            if (o < 32) xo[o] = a; else zo[o-32] = a;
        }
    }
}

// ---------------- K2: conv + silu + x_proj + dt + scan records ----------------
__global__ __launch_bounds__(128) void k2_conv(
    const float* __restrict__ xcp, const float* __restrict__ cw, const float* __restrict__ cb,
    const float* __restrict__ xpw, const float* __restrict__ dtw, const float* __restrict__ dtb,
    float* __restrict__ S)
{
    __shared__ float xt[131*33];
    __shared__ float cwl[128], cbl[32], xpl[33*32], dtwl[32], dtbl[32];
    int tid = threadIdx.x;
    int t0 = blockIdx.x*128; int n = blockIdx.y;
    const float* xb = xcp + (size_t)n*L4K*32;
    for (int f = tid; f < 131*32; f += 128) {
        int r = f >> 5, d = f & 31;
        int t = t0 - 3 + r;
        xt[r*33 + d] = (t >= 0) ? xb[(size_t)t*32 + d] : 0.f;
    }
    if (tid < 128) cwl[tid] = cw[tid];
    if (tid < 32) { cbl[tid] = cb[tid]; dtwl[tid] = dtw[tid]; dtbl[tid] = dtb[tid]; }
    for (int f = tid; f < 33*32; f += 128) xpl[f] = xpw[f];
    __syncthreads();
    int t = t0 + tid;
    float xc[32];
    #pragma unroll
    for (int d = 0; d < 32; ++d) {
        float sv = cbl[d];
        #pragma unroll
        for (int k = 0; k < 4; ++k) sv = fmaf(cwl[d*4+k], xt[(tid+k)*33 + d], sv);
        xc[d] = sv / (1.f + __expf(-sv));
    }
    float dtr = 0.f; float Bv[16], Cv[16];
    #pragma unroll
    for (int dd = 0; dd < 32; ++dd) dtr = fmaf(xc[dd], xpl[dd], dtr);
    #pragma unroll
    for (int o = 0; o < 16; ++o) {
        float a = 0.f, a2 = 0.f;
        #pragma unroll
        for (int dd = 0; dd < 32; ++dd) {
            a  = fmaf(xc[dd], xpl[(1+o)*32+dd],  a);
            a2 = fmaf(xc[dd], xpl[(17+o)*32+dd], a2);
        }
        Bv[o] = a; Cv[o] = a2;
    }
    float* r = S + ((size_t)n*L4K + t)*128;
    #pragma unroll
    for (int d = 0; d < 32; ++d) {
        float dv = fmaf(dtr, dtwl[d], dtbl[d]);
        float sp = fmaxf(dv, 0.f) + log1pf(__expf(-fabsf(dv)));
        r[d]      = sp;
        r[32 + d] = sp * xc[d];
        r[96 + d] = xc[d];
    }
    #pragma unroll
    for (int o = 0; o < 16; ++o) { r[64+o] = Bv[o]; r[80+o] = Cv[o]; }
}

// ---------------- K3a: chunk-local scan ----------------
__global__ __launch_bounds__(512) void k3a_local(
    const float* __restrict__ S, const float* __restrict__ alog,
    float* __restrict__ chunkA, float* __restrict__ chunkH)
{
    __shared__ float sb[2][TB*128];
    int tid = threadIdx.x;
    int d = tid >> 4, s = tid & 15;
    int chunk = blockIdx.x, n = blockIdx.y;
    float A = -__expf(alog[d*16 + s]);
    const float4* Sg = (const float4*)(S + ((size_t)n*L4K + (size_t)chunk*CL)*128);
    float4 p0 = Sg[tid], p1 = Sg[tid + 512];
    ((float4*)sb[0])[tid] = p0; ((float4*)sb[0])[tid+512] = p1;
    __syncthreads();
    float h = 0.f, ap = 1.f;
    for (int st = 0; st < NST; ++st) {
        int cur = st & 1;
        float4 q0, q1;
        if (st+1 < NST) {
            const float4* Sn = Sg + (size_t)(st+1)*TB*32;
            q0 = Sn[tid]; q1 = Sn[tid+512];
        }
        const float* sc = sb[cur];
        #pragma unroll
        for (int tl = 0; tl < TB; ++tl) {
            float dtv = sc[tl*128 + d];
            float dxv = sc[tl*128 + 32 + d];
            float Bvv = sc[tl*128 + 64 + s];
            float dA = __expf(dtv * A);
            h = fmaf(dA, h, dxv * Bvv);
            ap *= dA;
        }
        if (st+1 < NST) {
            ((float4*)sb[cur^1])[tid] = q0;
            ((float4*)sb[cur^1])[tid+512] = q1;
            __syncthreads();
        }
    }
    chunkA[(size_t)chunk*16384 + n*512 + tid] = ap;
    chunkH[(size_t)chunk*16384 + n*512 + tid] = h;
}

// ---------------- K3b: prefix across chunks ----------------
__global__ __launch_bounds__(256) void k3b_prefix(
    const float* __restrict__ chunkA, const float* __restrict__ chunkH,
    float* __restrict__ hstart)
{
    int nds = blockIdx.x*256 + threadIdx.x;
    float h = 0.f;
    hstart[nds] = 0.f;
    for (int c = 0; c < NCH-1; ++c) {
        h = fmaf(h, chunkA[(size_t)c*16384 + nds], chunkH[(size_t)c*16384 + nds]);
        hstart[(size_t)(c+1)*16384 + nds] = h;
    }
}

// ---------------- K3c: recompute with start state, emit y ----------------
__global__ __launch_bounds__(512) void k3c_emit(
    const float* __restrict__ S, const float* __restrict__ alog,
    const float* __restrict__ hstart, float* __restrict__ y)
{
    __shared__ float sb[2][TB*128];
    __shared__ float ys[TB*32];
    int tid = threadIdx.x;
    int d = tid >> 4, s = tid & 15;
    int chunk = blockIdx.x, n = blockIdx.y;
    float A = -__expf(alog[d*16 + s]);
    const float4* Sg = (const float4*)(S + ((size_t)n*L4K + (size_t)chunk*CL)*128);
    float4* yg = (float4*)(y + ((size_t)n*L4K + (size_t)chunk*CL)*32);
    float4 p0 = Sg[tid], p1 = Sg[tid + 512];
    ((float4*)sb[0])[tid] = p0; ((float4*)sb[0])[tid+512] = p1;
    float h = hstart[(size_t)chunk*16384 + n*512 + tid];
    __syncthreads();
    for (int st = 0; st < NST; ++st) {
        int cur = st & 1;
        float4 q0, q1;
        if (st+1 < NST) {
            const float4* Sn = Sg + (size_t)(st+1)*TB*32;
            q0 = Sn[tid]; q1 = Sn[tid+512];
        }
        const float* sc = sb[cur];
        #pragma unroll
        for (int tl = 0; tl < TB; ++tl) {
            float dtv = sc[tl*128 + d];
            float dxv = sc[tl*128 + 32 + d];
            float Bvv = sc[tl*128 + 64 + s];
            float Cvv = sc[tl*128 + 80 + s];
            float dA = __expf(dtv * A);
            h = fmaf(dA, h, dxv * Bvv);
            float p = h * Cvv;
            p += __shfl_xor(p, 8, 16);
            p += __shfl_xor(p, 4, 16);
            p += __shfl_xor(p, 2, 16);
            p += __shfl_xor(p, 1, 16);
            if (s == 0) ys[tl*32 + d] = p;
        }
        if (st+1 < NST) {
            ((float4*)sb[cur^1])[tid] = q0;
            ((float4*)sb[cur^1])[tid+512] = q1;
        }
        __syncthreads();
        if (tid < TB*8) yg[(size_t)st*TB*8 + tid] = ((const float4*)ys)[tid];
        __syncthreads();
    }
}

// ---------------- K5: gate + out_proj + residual -> m ----------------
__global__ __launch_bounds__(256) void k5_out(
    const float* __restrict__ y, const float* __restrict__ S, const float* __restrict__ zg,
    const float* __restrict__ zc, const float* __restrict__ Dp, const float* __restrict__ opw,
    float* __restrict__ m)
{
    int id = blockIdx.x*256 + threadIdx.x;
    int n = id >> 12, t = id & 4095;
    const float* yp  = y  + (size_t)id*32;
    const float* xcr = S  + (size_t)id*128 + 96;
    const float* zgp = zg + (size_t)id*32;
    const float* zcp = zc + (size_t)id*16;
    float v[32];
    #pragma unroll
    for (int dd = 0; dd < 32; ++dd) {
        float g = zgp[dd];
        float sig = 1.f/(1.f + __expf(-g));
        v[dd] = (yp[dd] + xcr[dd]*Dp[dd]) * (g*sig);
    }
    int b = n & 7, g4 = n >> 3;
    float* mp = m + ((size_t)b*L4K + t)*64 + g4*16;
    #pragma unroll
    for (int j = 0; j < 16; ++j) {
        float a = zcp[j];
        #pragma unroll
        for (int dd = 0; dd < 32; ++dd) a = fmaf(v[dd], opw[j*32+dd], a);
        mp[j] = a;
    }
}

// ---------------- K6: post-LN + bott_out; outp fp32 [c][l] + bf16 [l][c] ----
__global__ __launch_bounds__(256) void k6_post(
    const float* __restrict__ m, const float* __restrict__ x,
    const float* __restrict__ pog, const float* __restrict__ pob,
    const float* __restrict__ bow, const float* __restrict__ bob,
    const float* __restrict__ rsp, float* __restrict__ outp,
    unsigned short* __restrict__ outpb)
{
    __shared__ float ms[64*65];
    __shared__ float wl[128*64];
    __shared__ float pogs[64], pobs[64];
    int tid = threadIdx.x;
    int l0 = blockIdx.x*64, b = blockIdx.y;
    const float* mb = m + ((size_t)b*L4K + l0)*64;
    for (int f = tid; f < 4096; f += 256) {
        int i = f>>6, j = f&63;
        ms[i*65 + j] = mb[f];
    }
    for (int f = tid; f < 8192; f += 256) wl[f] = bow[f];
    if (tid < 64) { pogs[tid] = pog[tid]; pobs[tid] = pob[tid]; }
    __syncthreads();
    float rs = rsp[0];
    int i = tid & 63, q = tid >> 6;
    float s = 0.f, s2 = 0.f;
    for (int j = 0; j < 64; ++j) { float v = ms[i*65+j]; s += v; s2 = fmaf(v,v,s2); }
    float mn = s*(1.f/64.f);
    float rstd = rsqrtf(s2*(1.f/64.f) - mn*mn + 1e-5f);
    float acc[32];
    #pragma unroll
    for (int cc = 0; cc < 32; ++cc) acc[cc] = bob[q*32+cc];
    for (int j = 0; j < 64; ++j) {
        float v = (ms[i*65+j]-mn)*rstd*pogs[j] + pobs[j];
        #pragma unroll
        for (int cc = 0; cc < 32; ++cc) acc[cc] = fmaf(v, wl[(q*32+cc)*64+j], acc[cc]);
    }
    const float* xb = x + (size_t)b*128*L4K + l0 + i;
    float* ob = outp + (size_t)b*128*L4K + l0 + i;
    unsigned short pk[32];
    #pragma unroll
    for (int cc = 0; cc < 32; ++cc) {
        int c = q*32 + cc;
        float val = 2.f*xb[(size_t)c*L4K] + acc[cc]*rs;
        ob[(size_t)c*L4K] = val;
        pk[cc] = f2b(val);
    }
    uint4* op = (uint4*)&outpb[((size_t)b*L4K + l0 + i)*128 + q*32];
    #pragma unroll
    for (int u = 0; u < 4; ++u) {
        uint4 v;
        v.x = pk[u*8+0] | ((unsigned)pk[u*8+1]<<16);
        v.y = pk[u*8+2] | ((unsigned)pk[u*8+3]<<16);
        v.z = pk[u*8+4] | ((unsigned)pk[u*8+5]<<16);
        v.w = pk[u*8+6] | ((unsigned)pk[u*8+7]<<16);
        op[u] = v;
    }
}

// ---------------- MFMA GEMM: D[l][n] = A[l][k] * W[n][k]^T ----------------
// A: bf16 [B*4096][Kpitch]; W: fp32 [Ntot][KCHUNKS*128]; D: bf16 or fp32 [B*4096][Npitch]
template<int KCHUNKS, bool OUT_BF16>
__global__ __launch_bounds__(256) void gemm_mfma(
    const unsigned short* __restrict__ Ab, const float* __restrict__ Wg,
    void* __restrict__ Dout, int Kpitch, int Npitch)
{
    __shared__ char lds[65536];
    int tid = threadIdx.x;
    int lane = tid & 63, w = tid >> 6;
    int l0 = blockIdx.x * 128, n0 = blockIdx.y * 128, b = blockIdx.z;
    size_t arow0 = (size_t)b*L4K + l0;
    int wm = (w>>1)*64, wn = (w&1)*64;
    f32x4 acc[4][4] = {};
    char* aL = lds;
    char* wL = lds + 32768;
    for (int kc = 0; kc < KCHUNKS; ++kc) {
        if (kc) __syncthreads();
        #pragma unroll
        for (int it = 0; it < 8; ++it) {
            int f = it*256 + tid;
            int row = f >> 4, kp = f & 15;
            uint4 v = *(const uint4*)&Ab[(arow0 + row)*(size_t)Kpitch + kc*128 + kp*8];
            int off = row*256 + kp*16; off ^= (row&7)<<4;
            *(uint4*)(aL + off) = v;
        }
        #pragma unroll
        for (int it = 0; it < 16; ++it) {
            int f = it*256 + tid;
            int row = f >> 5, kg = f & 31;
            float4 v = *(const float4*)&Wg[(size_t)(n0+row)*(KCHUNKS*128) + kc*128 + kg*4];
            uint2 p;
            p.x = f2b(v.x) | ((unsigned)f2b(v.y)<<16);
            p.y = f2b(v.z) | ((unsigned)f2b(v.w)<<16);
            int off = row*256 + kg*8; off ^= (row&7)<<4;
            *(uint2*)(wL + off) = p;
        }
        __syncthreads();
        #pragma unroll
        for (int ks = 0; ks < 4; ++ks) {
            short8 af[4], wf[4];
            int kb = ks*64 + (lane>>4)*16;
            #pragma unroll
            for (int mi = 0; mi < 4; ++mi) {
                int row = wm + mi*16 + (lane&15);
                int off = row*256 + kb; off ^= (row&7)<<4;
                af[mi] = *(const short8*)(aL + off);
            }
            #pragma unroll
            for (int ni = 0; ni < 4; ++ni) {
                int row = wn + ni*16 + (lane&15);
                int off = row*256 + kb; off ^= (row&7)<<4;
                wf[ni] = *(const short8*)(wL + off);
            }
            #pragma unroll
            for (int mi = 0; mi < 4; ++mi)
                #pragma unroll
                for (int ni = 0; ni < 4; ++ni)
                    acc[mi][ni] = __builtin_amdgcn_mfma_f32_16x16x32_bf16(af[mi], wf[ni], acc[mi][ni], 0, 0, 0);
        }
    }
    if (OUT_BF16) {
        __syncthreads();
        unsigned short* cL = (unsigned short*)lds;   // [128][136]
        #pragma unroll
        for (int mi = 0; mi < 4; ++mi)
            #pragma unroll
            for (int ni = 0; ni < 4; ++ni)
                #pragma unroll
                for (int r = 0; r < 4; ++r) {
                    int row = wm + mi*16 + (lane>>4)*4 + r;
                    int col = wn + ni*16 + (lane&15);
                    cL[row*136 + col] = f2b(acc[mi][ni][r]);
                }
        __syncthreads();
        unsigned short* D = (unsigned short*)Dout;
        #pragma unroll
        for (int it = 0; it < 8; ++it) {
            int f = it*256 + tid;
            int row = f >> 4, kp = f & 15;
            uint4 v = *(const uint4*)&cL[row*136 + kp*8];
            *(uint4*)&D[(arow0 + row)*(size_t)Npitch + n0 + kp*8] = v;
        }
    } else {
        float* D = (float*)Dout;
        #pragma unroll
        for (int mi = 0; mi < 4; ++mi)
            #pragma unroll
            for (int ni = 0; ni < 4; ++ni)
                #pragma unroll
                for (int r = 0; r < 4; ++r) {
                    int row = wm + mi*16 + (lane>>4)*4 + r;
                    int col = wn + ni*16 + (lane&15);
                    D[(arow0 + row)*(size_t)Npitch + n0 + col] = acc[mi][ni][r];
                }
    }
}

// ---------------- GN1 stats over bf16 h1t [l][512], 16 ch/group ----------------
__global__ __launch_bounds__(256) void k_gn1stats(
    const unsigned short* __restrict__ h, float* __restrict__ stats)
{
    __shared__ float sred[256], sred2[256];
    int tid = threadIdx.x;
    int b = blockIdx.x >> 5, g = blockIdx.x & 31;
    float s = 0.f, s2 = 0.f;
    for (int it = 0; it < 32; ++it) {
        int f = it*256 + tid;
        int l = f >> 1, half = f & 1;
        uint4 v = *(const uint4*)&h[((size_t)b*L4K + l)*512 + g*16 + half*8];
        unsigned int ws[4] = {v.x, v.y, v.z, v.w};
        #pragma unroll
        for (int u = 0; u < 4; ++u) {
            float a = b2f((unsigned short)(ws[u] & 0xFFFF));
            float c = b2f((unsigned short)(ws[u] >> 16));
            s += a + c; s2 = fmaf(a,a,s2); s2 = fmaf(c,c,s2);
        }
    }
    sred[tid] = s; sred2[tid] = s2; __syncthreads();
    for (int off = 128; off; off >>= 1) {
        if (tid < off) { sred[tid] += sred[tid+off]; sred2[tid] += sred2[tid+off]; }
        __syncthreads();
    }
    if (tid == 0) {
        float inv = 1.f/65536.f;
        float mn = sred[0]*inv;
        float var = sred2[0]*inv - mn*mn;
        stats[blockIdx.x*2]   = mn;
        stats[blockIdx.x*2+1] = rsqrtf(var + 1e-5f);
    }
}

// ---------------- K9: gn1 apply + exact gelu, in-place bf16 [l][512] --------
__global__ __launch_bounds__(256) void k9_gngelu(
    unsigned short* __restrict__ h, const float* __restrict__ stats,
    const float* __restrict__ g1, const float* __restrict__ b1)
{
    size_t idx = ((size_t)blockIdx.x*256 + threadIdx.x)*8;
    int o0 = (int)(idx & 511);
    int b = (int)(idx >> 21);
    int sg = b*32 + (o0 >> 4);
    float mn = stats[sg*2], rstd = stats[sg*2+1];
    uint4 v = *(uint4*)&h[idx];
    unsigned int ws[4] = {v.x, v.y, v.z, v.w};
    unsigned int out[4];
    #pragma unroll
    for (int u = 0; u < 4; ++u) {
        float a = b2f((unsigned short)(ws[u] & 0xFFFF));
        float c = b2f((unsigned short)(ws[u] >> 16));
        int o = o0 + u*2;
        float ta = (a-mn)*rstd*g1[o]   + b1[o];
        float tc = (c-mn)*rstd*g1[o+1] + b1[o+1];
        ta = 0.5f*ta*(1.f + erff(ta*0.70710678118654752f));
        tc = 0.5f*tc*(1.f + erff(tc*0.70710678118654752f));
        out[u] = f2b(ta) | ((unsigned)f2b(tc)<<16);
    }
    uint4 r; r.x = out[0]; r.y = out[1]; r.z = out[2]; r.w = out[3];
    *(uint4*)&h[idx] = r;
}

// ---------------- GN2 stats over fp32 h2t [l][128], 4 ch/group ----------------
__global__ __launch_bounds__(256) void k_gn2stats(
    const float* __restrict__ h, float* __restrict__ stats)
{
    __shared__ float sred[256], sred2[256];
    int tid = threadIdx.x;
    int b = blockIdx.x >> 5, g = blockIdx.x & 31;
    float s = 0.f, s2 = 0.f;
    for (int it = 0; it < 16; ++it) {
        int l = it*256 + tid;
        float4 v = ((const float4*)h)[((size_t)b*L4K + l)*32 + g];
        s += v.x+v.y+v.z+v.w;
        s2 = fmaf(v.x,v.x,s2); s2 = fmaf(v.y,v.y,s2); s2 = fmaf(v.z,v.z,s2); s2 = fmaf(v.w,v.w,s2);
    }
    sred[tid] = s; sred2[tid] = s2; __syncthreads();
    for (int off = 128; off; off >>= 1) {
        if (tid < off) { sred[tid] += sred[tid+off]; sred2[tid] += sred2[tid+off]; }
        __syncthreads();
    }
    if (tid == 0) {
        float inv = 1.f/16384.f;
        float mn = sred[0]*inv;
        float var = sred2[0]*inv - mn*mn;
        stats[blockIdx.x*2]   = mn;
        stats[blockIdx.x*2+1] = rsqrtf(var + 1e-5f);
    }
}

// ---------------- K12: out[c][l] = outp[c][l] + gn2(h2t[l][c]) (transpose) ----
__global__ __launch_bounds__(256) void k12_final(
    const float* __restrict__ outp, const float* __restrict__ h2t,
    const float* __restrict__ stats, const float* __restrict__ g2,
    const float* __restrict__ b2, float* __restrict__ out)
{
    __shared__ float T[32*33];
    int tid = threadIdx.x;
    int l0 = blockIdx.x*32, c0 = blockIdx.y*32, b = blockIdx.z;
    {
        int i = tid >> 3, jq = tid & 7;
        float4 v = ((const float4*)h2t)[((size_t)b*L4K + l0 + i)*32 + (c0>>2) + jq];
        int sg = b*32 + (c0>>2) + jq;
        float mn = stats[sg*2], rstd = stats[sg*2+1];
        int c = c0 + jq*4;
        T[(jq*4+0)*33 + i] = (v.x-mn)*rstd*g2[c+0] + b2[c+0];
        T[(jq*4+1)*33 + i] = (v.y-mn)*rstd*g2[c+1] + b2[c+1];
        T[(jq*4+2)*33 + i] = (v.z-mn)*rstd*g2[c+2] + b2[c+2];
        T[(jq*4+3)*33 + i] = (v.w-mn)*rstd*g2[c+3] + b2[c+3];
    }
    __syncthreads();
    {
        int c = tid >> 3, iq = tid & 7;
        size_t gi = ((size_t)b*128 + c0 + c)*1024 + (l0>>2) + iq;
        float4 o = ((const float4*)outp)[gi];
        float4 r;
        r.x = o.x + T[c*33 + iq*4 + 0];
        r.y = o.y + T[c*33 + iq*4 + 1];
        r.z = o.z + T[c*33 + iq*4 + 2];
        r.w = o.w + T[c*33 + iq*4 + 3];
        ((float4*)out)[gi] = r;
    }
}

extern "C" void kernel_launch(void* const* d_in, const int* in_sizes, int n_in,
                              void* d_out, int out_size, void* d_ws, size_t ws_size,
                              hipStream_t stream) {
    (void)in_sizes; (void)n_in; (void)out_size; (void)ws_size;
    const float* x    = (const float*)d_in[0];
    const float* png  = (const float*)d_in[1];
    const float* pnb  = (const float*)d_in[2];
    const float* biw  = (const float*)d_in[3];
    const float* bib  = (const float*)d_in[4];
    const float* ipw  = (const float*)d_in[5];
    const float* cw   = (const float*)d_in[6];
    const float* cb   = (const float*)d_in[7];
    const float* xpw  = (const float*)d_in[8];
    const float* dtw  = (const float*)d_in[9];
    const float* dtb  = (const float*)d_in[10];
    const float* alog = (const float*)d_in[11];
    const float* Dp   = (const float*)d_in[12];
    const float* opw  = (const float*)d_in[13];
    const float* pog  = (const float*)d_in[14];
    const float* pob  = (const float*)d_in[15];
    const float* bow  = (const float*)d_in[16];
    const float* bob  = (const float*)d_in[17];
    const float* rsp  = (const float*)d_in[18];
    const float* f1w  = (const float*)d_in[19];
    const float* g1g  = (const float*)d_in[20];
    const float* g1b  = (const float*)d_in[21];
    const float* f2w  = (const float*)d_in[22];
    const float* g2g  = (const float*)d_in[23];
    const float* g2b  = (const float*)d_in[24];

    char* ws = (char*)d_ws;
    // Phase 1 (mamba), peak 112 MiB:
    float* S    = (float*)(ws + 0);            // 64 MB, dead after k5
    float* zc   = (float*)(ws + 67108864);     // 8 MB,  dead after k5
    float* zg   = (float*)(ws + 75497472);     // 16 MB, dead after k5
    float* xcp  = (float*)(ws + 92274688);     // 16 MB, dead after k2
    float* y    = (float*)(ws + 92274688);     // aliases xcp
    float* m    = (float*)(ws + 109051904);    // 8 MB (k5->k6)
    float* chA  = (float*)(ws + 109051904);                // 2 MB (pre-k5)
    float* chH  = (float*)(ws + 109051904 + 2097152);      // 2 MB
    float* hst  = (float*)(ws + 109051904 + 4194304);      // 2 MB
    // Phase 2 (post): all alias dead phase-1 regions
    float*          outp  = (float*)(ws + 0);              // 16 MB fp32 [c][l]
    unsigned short* outpb = (unsigned short*)(ws + 16777216); // 8 MB bf16 [l][c]
    unsigned short* h1tb  = (unsigned short*)(ws + 25165824); // 32 MB bf16 [l][512]
    float*          h2t   = (float*)(ws + 58720256);       // 16 MB fp32 [l][128]
    float*          st1   = (float*)(ws + 75497472);       // 2 KB (zg dead)
    float*          st2   = (float*)(ws + 75501568);

    k1_pre<<<dim3(128,8),256,0,stream>>>(x,png,pnb,biw,bib,ipw,zc,xcp,zg);
    k2_conv<<<dim3(32,32),128,0,stream>>>(xcp,cw,cb,xpw,dtw,dtb,S);
    k3a_local<<<dim3(NCH,32),512,0,stream>>>(S,alog,chA,chH);
    k3b_prefix<<<64,256,0,stream>>>(chA,chH,hst);
    k3c_emit<<<dim3(NCH,32),512,0,stream>>>(S,alog,hst,y);
    k5_out<<<512,256,0,stream>>>(y,S,zg,zc,Dp,opw,m);
    k6_post<<<dim3(64,8),256,0,stream>>>(m,x,pog,pob,bow,bob,rsp,outp,outpb);
    gemm_mfma<1,true><<<dim3(32,4,8),256,0,stream>>>(outpb,f1w,(void*)h1tb,128,512);
    k_gn1stats<<<256,256,0,stream>>>(h1tb,st1);
    k9_gngelu<<<8192,256,0,stream>>>(h1tb,st1,g1g,g1b);
    gemm_mfma<4,false><<<dim3(32,1,8),256,0,stream>>>(h1tb,f2w,(void*)h2t,512,128);
    k_gn2stats<<<256,256,0,stream>>>(h2t,st2);
    k12_final<<<dim3(128,4,8),256,0,stream>>>(outp,h2t,st2,g2g,g2b,(float*)d_out);
}

// Round 7
// 460.071 us; speedup vs baseline: 4.3765x; 1.0357x over previous
//
#include <hip/hip_runtime.h>
#include <hip/hip_bf16.h>
#include <math.h>

#define L4K 4096
#define NCH 32     // scan chunks over L
#define CL  128    // timesteps per chunk
#define SPN (128*4096)   // floats per n in S planes

typedef __attribute__((ext_vector_type(8))) short short8;
typedef __attribute__((ext_vector_type(4))) float f32x4;

__device__ __forceinline__ unsigned short f2b(float f) {
    unsigned int u = __float_as_uint(f);
    unsigned int r = u + 0x7FFFu + ((u >> 16) & 1u);
    return (unsigned short)(r >> 16);
}
__device__ __forceinline__ float b2f(unsigned short h) {
    return __uint_as_float(((unsigned int)h) << 16);
}
// sum over each 16-lane row via DPP row_ror (VALU pipe, no LDS)
__device__ __forceinline__ float rowsum16(float p) {
    int t;
    t = __builtin_amdgcn_update_dpp(0, __float_as_int(p), 0x128, 0xf, 0xf, false);
    p += __int_as_float(t);
    t = __builtin_amdgcn_update_dpp(0, __float_as_int(p), 0x124, 0xf, 0xf, false);
    p += __int_as_float(t);
    t = __builtin_amdgcn_update_dpp(0, __float_as_int(p), 0x122, 0xf, 0xf, false);
    p += __int_as_float(t);
    t = __builtin_amdgcn_update_dpp(0, __float_as_int(p), 0x121, 0xf, 0xf, false);
    p += __int_as_float(t);
    return p;
}

// ---------------- K1: pre-LN + bott_in + in_proj (plane outputs) ----------------
__global__ __launch_bounds__(256) void k1_pre(
    const float* __restrict__ x, const float* __restrict__ png, const float* __restrict__ pnb,
    const float* __restrict__ biw, const float* __restrict__ bib, const float* __restrict__ ipw,
    float* __restrict__ zc, float* __restrict__ xcp, float* __restrict__ zg)
{
    __shared__ float xs[128*32];
    __shared__ float wl[64*128];
    __shared__ float zs[32*65];
    __shared__ float ipl[64*16];
    __shared__ float pngs[128], pnbs[128];
    int tid = threadIdx.x;
    int l0 = blockIdx.x*32, b = blockIdx.y;
    const float* xb = x + (size_t)b*128*L4K;
    for (int it = 0; it < 16; ++it) {
        int f = it*256 + tid; int c = f>>5, i = f&31;
        xs[f] = xb[(size_t)c*L4K + l0 + i];
    }
    for (int f = tid; f < 8192; f += 256) wl[f] = biw[f];
    for (int f = tid; f < 1024; f += 256) ipl[f] = ipw[f];
    if (tid < 128) { pngs[tid] = png[tid]; pnbs[tid] = pnb[tid]; }
    __syncthreads();
    int i = tid & 31, q = tid >> 5;
    float s = 0.f, s2 = 0.f;
    for (int c = 0; c < 128; ++c) { float v = xs[c*32+i]; s += v; s2 = fmaf(v,v,s2); }
    float mn = s*(1.f/128.f);
    float rstd = rsqrtf(s2*(1.f/128.f) - mn*mn + 1e-5f);
    float z[8];
    #pragma unroll
    for (int jj = 0; jj < 8; ++jj) z[jj] = bib[q*8+jj];
    for (int c = 0; c < 128; ++c) {
        float xv = (xs[c*32+i] - mn)*rstd*pngs[c] + pnbs[c];
        #pragma unroll
        for (int jj = 0; jj < 8; ++jj) z[jj] = fmaf(xv, wl[(q*8+jj)*128 + c], z[jj]);
    }
    #pragma unroll
    for (int jj = 0; jj < 8; ++jj) zs[i*65 + q*8 + jj] = z[jj];
    __syncthreads();
    if (tid < 128) {
        int i2 = tid & 31, g = tid >> 5;
        int n = g*8 + b; int l = l0 + i2;
        float zv[16];
        #pragma unroll
        for (int k = 0; k < 16; ++k) zv[k] = zs[i2*65 + g*16 + k];
        float* zcb = zc + ((size_t)n*16)*L4K + l;
        #pragma unroll
        for (int k = 0; k < 16; ++k) zcb[(size_t)k*L4K] = zv[k];
        float* xo = xcp + ((size_t)n*32)*L4K + l;
        float* zo = zg  + ((size_t)n*32)*L4K + l;
        #pragma unroll
        for (int o = 0; o < 64; ++o) {
            float a = 0.f;
            #pragma unroll
            for (int k = 0; k < 16; ++k) a = fmaf(zv[k], ipl[o*16+k], a);
            if (o < 32) xo[(size_t)o*L4K] = a; else zo[(size_t)(o-32)*L4K] = a;
        }
    }
}

// ---------------- K2: conv + silu + x_proj + dt -> S planes ----------------
// S planes per n (stride SPN): [0:32)=dt, [32:64)=dx, [64:80)=B, [80:96)=C, [96:128)=xc
__global__ __launch_bounds__(128) void k2_conv(
    const float* __restrict__ xcp, const float* __restrict__ cw, const float* __restrict__ cb,
    const float* __restrict__ xpw, const float* __restrict__ dtw, const float* __restrict__ dtb,
    float* __restrict__ S)
{
    __shared__ float xt[131*33];
    __shared__ float cwl[128], cbl[32], xpl[33*32], dtwl[32], dtbl[32];
    int tid = threadIdx.x;
    int t0 = blockIdx.x*128; int n = blockIdx.y;
    const float* xb = xcp + (size_t)n*32*L4K;
    #pragma unroll 4
    for (int d = 0; d < 32; ++d) {
        int t = t0 - 3 + tid;
        xt[tid*33 + d] = (t >= 0) ? xb[(size_t)d*L4K + t] : 0.f;
        if (tid < 3) {
            int r = 128 + tid; int t2 = t0 - 3 + r;
            xt[r*33 + d] = xb[(size_t)d*L4K + t2];
        }
    }
    if (tid < 128) cwl[tid] = cw[tid];
    if (tid < 32) { cbl[tid] = cb[tid]; dtwl[tid] = dtw[tid]; dtbl[tid] = dtb[tid]; }
    for (int f = tid; f < 33*32; f += 128) xpl[f] = xpw[f];
    __syncthreads();
    int t = t0 + tid;
    float xc[32];
    #pragma unroll
    for (int d = 0; d < 32; ++d) {
        float sv = cbl[d];
        #pragma unroll
        for (int k = 0; k < 4; ++k) sv = fmaf(cwl[d*4+k], xt[(tid+k)*33 + d], sv);
        xc[d] = sv / (1.f + __expf(-sv));
    }
    float dtr = 0.f; float Bv[16], Cv[16];
    #pragma unroll
    for (int dd = 0; dd < 32; ++dd) dtr = fmaf(xc[dd], xpl[dd], dtr);
    #pragma unroll
    for (int o = 0; o < 16; ++o) {
        float a = 0.f, a2 = 0.f;
        #pragma unroll
        for (int dd = 0; dd < 32; ++dd) {
            a  = fmaf(xc[dd], xpl[(1+o)*32+dd],  a);
            a2 = fmaf(xc[dd], xpl[(17+o)*32+dd], a2);
        }
        Bv[o] = a; Cv[o] = a2;
    }
    float* Sn = S + (size_t)n*SPN + t;
    #pragma unroll
    for (int d = 0; d < 32; ++d) {
        float dv = fmaf(dtr, dtwl[d], dtbl[d]);
        float sp = fmaxf(dv, 0.f) + log1pf(__expf(-fabsf(dv)));
        Sn[(size_t)d*L4K]      = sp;
        Sn[(size_t)(32+d)*L4K] = sp * xc[d];
        Sn[(size_t)(96+d)*L4K] = xc[d];
    }
    #pragma unroll
    for (int o = 0; o < 16; ++o) {
        Sn[(size_t)(64+o)*L4K] = Bv[o];
        Sn[(size_t)(80+o)*L4K] = Cv[o];
    }
}

// ---------------- K3a: chunk-local scan (register-streamed, no LDS) ----------
__global__ __launch_bounds__(512) void k3a_local(
    const float* __restrict__ S, const float* __restrict__ alog,
    float* __restrict__ chunkA, float* __restrict__ chunkH)
{
    int tid = threadIdx.x;
    int d = tid >> 4, s = tid & 15;
    int chunk = blockIdx.x, n = blockIdx.y;
    float A = -__expf(alog[d*16 + s]);
    const float* base = S + (size_t)n*SPN + (size_t)chunk*CL;
    const float4* pdt = (const float4*)(base + (size_t)d*L4K);
    const float4* pdx = (const float4*)(base + (size_t)(32+d)*L4K);
    const float4* pB  = (const float4*)(base + (size_t)(64+s)*L4K);
    float4 cdt = pdt[0], cdx = pdx[0], cB = pB[0];
    float h = 0.f, ap = 1.f;
    #define A_STEP(c1,c2,c3) { float dA = __expf(c1*A); h = fmaf(dA, h, c2*c3); ap *= dA; }
    for (int i = 0; i < CL/4 - 1; ++i) {
        float4 ndt = pdt[i+1], ndx = pdx[i+1], nB = pB[i+1];
        A_STEP(cdt.x, cdx.x, cB.x) A_STEP(cdt.y, cdx.y, cB.y)
        A_STEP(cdt.z, cdx.z, cB.z) A_STEP(cdt.w, cdx.w, cB.w)
        cdt = ndt; cdx = ndx; cB = nB;
    }
    A_STEP(cdt.x, cdx.x, cB.x) A_STEP(cdt.y, cdx.y, cB.y)
    A_STEP(cdt.z, cdx.z, cB.z) A_STEP(cdt.w, cdx.w, cB.w)
    #undef A_STEP
    size_t idx = (size_t)chunk*16384 + n*512 + tid;
    chunkA[idx] = ap;
    chunkH[idx] = h;
}

// ---------------- K3b: prefix across chunks ----------------
__global__ __launch_bounds__(256) void k3b_prefix(
    const float* __restrict__ chunkA, const float* __restrict__ chunkH,
    float* __restrict__ hstart)
{
    int nds = blockIdx.x*256 + threadIdx.x;
    float h = 0.f;
    hstart[nds] = 0.f;
    for (int c = 0; c < NCH-1; ++c) {
        h = fmaf(h, chunkA[(size_t)c*16384 + nds], chunkH[(size_t)c*16384 + nds]);
        hstart[(size_t)(c+1)*16384 + nds] = h;
    }
}

// ---------------- K3c: recompute with start state, emit y planes ------------
__global__ __launch_bounds__(512) void k3c_emit(
    const float* __restrict__ S, const float* __restrict__ alog,
    const float* __restrict__ hstart, float* __restrict__ y)
{
    int tid = threadIdx.x;
    int d = tid >> 4, s = tid & 15;
    int chunk = blockIdx.x, n = blockIdx.y;
    float A = -__expf(alog[d*16 + s]);
    const float* base = S + (size_t)n*SPN + (size_t)chunk*CL;
    const float4* pdt = (const float4*)(base + (size_t)d*L4K);
    const float4* pdx = (const float4*)(base + (size_t)(32+d)*L4K);
    const float4* pB  = (const float4*)(base + (size_t)(64+s)*L4K);
    const float4* pC  = (const float4*)(base + (size_t)(80+s)*L4K);
    float4* yb = (float4*)(y + ((size_t)n*32 + d)*L4K + (size_t)chunk*CL);
    float4 cdt = pdt[0], cdx = pdx[0], cB = pB[0], cC = pC[0];
    float h = hstart[(size_t)chunk*16384 + n*512 + tid];
    #define C_STEP(c1,c2,c3,c4,dst) { float dA = __expf(c1*A); h = fmaf(dA, h, c2*c3); dst = rowsum16(h*c4); }
    for (int i = 0; i < CL/4 - 1; ++i) {
        float4 ndt = pdt[i+1], ndx = pdx[i+1], nB = pB[i+1], nC = pC[i+1];
        float4 yv;
        C_STEP(cdt.x, cdx.x, cB.x, cC.x, yv.x)
        C_STEP(cdt.y, cdx.y, cB.y, cC.y, yv.y)
        C_STEP(cdt.z, cdx.z, cB.z, cC.z, yv.z)
        C_STEP(cdt.w, cdx.w, cB.w, cC.w, yv.w)
        if (s == 0) yb[i] = yv;
        cdt = ndt; cdx = ndx; cB = nB; cC = nC;
    }
    {
        float4 yv;
        C_STEP(cdt.x, cdx.x, cB.x, cC.x, yv.x)
        C_STEP(cdt.y, cdx.y, cB.y, cC.y, yv.y)
        C_STEP(cdt.z, cdx.z, cB.z, cC.z, yv.z)
        C_STEP(cdt.w, cdx.w, cB.w, cC.w, yv.w)
        if (s == 0) yb[CL/4 - 1] = yv;
    }
    #undef C_STEP
}

// ---------------- K5: gate + out_proj + residual -> m planes ----------------
__global__ __launch_bounds__(256) void k5_out(
    const float* __restrict__ y, const float* __restrict__ S, const float* __restrict__ zg,
    const float* __restrict__ zc, const float* __restrict__ Dp, const float* __restrict__ opw,
    float* __restrict__ m)
{
    int id = blockIdx.x*256 + threadIdx.x;
    int n = id >> 12, t = id & 4095;
    const float* yb  = y  + (size_t)n*32*L4K + t;
    const float* xcb = S  + (size_t)n*SPN + (size_t)96*L4K + t;
    const float* zgb = zg + (size_t)n*32*L4K + t;
    const float* zcb = zc + (size_t)n*16*L4K + t;
    float v[32];
    #pragma unroll
    for (int dd = 0; dd < 32; ++dd) {
        float g = zgb[(size_t)dd*L4K];
        float sig = 1.f/(1.f + __expf(-g));
        v[dd] = (yb[(size_t)dd*L4K] + xcb[(size_t)dd*L4K]*Dp[dd]) * (g*sig);
    }
    int b = n & 7, g4 = n >> 3;
    float* mp = m + ((size_t)b*64 + g4*16)*L4K + t;
    #pragma unroll
    for (int j = 0; j < 16; ++j) {
        float a = zcb[(size_t)j*L4K];
        #pragma unroll
        for (int dd = 0; dd < 32; ++dd) a = fmaf(v[dd], opw[j*32+dd], a);
        mp[(size_t)j*L4K] = a;
    }
}

// ---------------- K6: post-LN + bott_out; outp fp32 [c][l] + bf16 [l][c] ----
__global__ __launch_bounds__(256) void k6_post(
    const float* __restrict__ m, const float* __restrict__ x,
    const float* __restrict__ pog, const float* __restrict__ pob,
    const float* __restrict__ bow, const float* __restrict__ bob,
    const float* __restrict__ rsp, float* __restrict__ outp,
    unsigned short* __restrict__ outpb)
{
    __shared__ float ms[64*65];
    __shared__ float wl[128*64];
    __shared__ float pogs[64], pobs[64];
    int tid = threadIdx.x;
    int l0 = blockIdx.x*64, b = blockIdx.y;
    for (int f = tid; f < 4096; f += 256) {
        int i = f & 63, j = f >> 6;
        ms[i*65 + j] = m[((size_t)b*64 + j)*L4K + l0 + i];
    }
    for (int f = tid; f < 8192; f += 256) wl[f] = bow[f];
    if (tid < 64) { pogs[tid] = pog[tid]; pobs[tid] = pob[tid]; }
    __syncthreads();
    float rs = rsp[0];
    int i = tid & 63, q = tid >> 6;
    float s = 0.f, s2 = 0.f;
    for (int j = 0; j < 64; ++j) { float v = ms[i*65+j]; s += v; s2 = fmaf(v,v,s2); }
    float mn = s*(1.f/64.f);
    float rstd = rsqrtf(s2*(1.f/64.f) - mn*mn + 1e-5f);
    float acc[32];
    #pragma unroll
    for (int cc = 0; cc < 32; ++cc) acc[cc] = bob[q*32+cc];
    for (int j = 0; j < 64; ++j) {
        float v = (ms[i*65+j]-mn)*rstd*pogs[j] + pobs[j];
        #pragma unroll
        for (int cc = 0; cc < 32; ++cc) acc[cc] = fmaf(v, wl[(q*32+cc)*64+j], acc[cc]);
    }
    const float* xb = x + (size_t)b*128*L4K + l0 + i;
    float* ob = outp + (size_t)b*128*L4K + l0 + i;
    unsigned short pk[32];
    #pragma unroll
    for (int cc = 0; cc < 32; ++cc) {
        int c = q*32 + cc;
        float val = 2.f*xb[(size_t)c*L4K] + acc[cc]*rs;
        ob[(size_t)c*L4K] = val;
        pk[cc] = f2b(val);
    }
    uint4* op = (uint4*)&outpb[((size_t)b*L4K + l0 + i)*128 + q*32];
    #pragma unroll
    for (int u = 0; u < 4; ++u) {
        uint4 v;
        v.x = pk[u*8+0] | ((unsigned)pk[u*8+1]<<16);
        v.y = pk[u*8+2] | ((unsigned)pk[u*8+3]<<16);
        v.z = pk[u*8+4] | ((unsigned)pk[u*8+5]<<16);
        v.w = pk[u*8+6] | ((unsigned)pk[u*8+7]<<16);
        op[u] = v;
    }
}

// ---------------- MFMA GEMM: D[l][n] = A[l][k] * W[n][k]^T ----------------
template<int KCHUNKS, bool OUT_BF16>
__global__ __launch_bounds__(256) void gemm_mfma(
    const unsigned short* __restrict__ Ab, const float* __restrict__ Wg,
    void* __restrict__ Dout, int Kpitch, int Npitch)
{
    __shared__ char lds[65536];
    int tid = threadIdx.x;
    int lane = tid & 63, w = tid >> 6;
    int l0 = blockIdx.x * 128, n0 = blockIdx.y * 128, b = blockIdx.z;
    size_t arow0 = (size_t)b*L4K + l0;
    int wm = (w>>1)*64, wn = (w&1)*64;
    f32x4 acc[4][4] = {};
    char* aL = lds;
    char* wL = lds + 32768;
    for (int kc = 0; kc < KCHUNKS; ++kc) {
        if (kc) __syncthreads();
        #pragma unroll
        for (int it = 0; it < 8; ++it) {
            int f = it*256 + tid;
            int row = f >> 4, kp = f & 15;
            uint4 v = *(const uint4*)&Ab[(arow0 + row)*(size_t)Kpitch + kc*128 + kp*8];
            int off = row*256 + kp*16; off ^= (row&7)<<4;
            *(uint4*)(aL + off) = v;
        }
        #pragma unroll
        for (int it = 0; it < 16; ++it) {
            int f = it*256 + tid;
            int row = f >> 5, kg = f & 31;
            float4 v = *(const float4*)&Wg[(size_t)(n0+row)*(KCHUNKS*128) + kc*128 + kg*4];
            uint2 p;
            p.x = f2b(v.x) | ((unsigned)f2b(v.y)<<16);
            p.y = f2b(v.z) | ((unsigned)f2b(v.w)<<16);
            int off = row*256 + kg*8; off ^= (row&7)<<4;
            *(uint2*)(wL + off) = p;
        }
        __syncthreads();
        #pragma unroll
        for (int ks = 0; ks < 4; ++ks) {
            short8 af[4], wf[4];
            int kb = ks*64 + (lane>>4)*16;
            #pragma unroll
            for (int mi = 0; mi < 4; ++mi) {
                int row = wm + mi*16 + (lane&15);
                int off = row*256 + kb; off ^= (row&7)<<4;
                af[mi] = *(const short8*)(aL + off);
            }
            #pragma unroll
            for (int ni = 0; ni < 4; ++ni) {
                int row = wn + ni*16 + (lane&15);
                int off = row*256 + kb; off ^= (row&7)<<4;
                wf[ni] = *(const short8*)(wL + off);
            }
            #pragma unroll
            for (int mi = 0; mi < 4; ++mi)
                #pragma unroll
                for (int ni = 0; ni < 4; ++ni)
                    acc[mi][ni] = __builtin_amdgcn_mfma_f32_16x16x32_bf16(af[mi], wf[ni], acc[mi][ni], 0, 0, 0);
        }
    }
    if (OUT_BF16) {
        __syncthreads();
        unsigned short* cL = (unsigned short*)lds;   // [128][136]
        #pragma unroll
        for (int mi = 0; mi < 4; ++mi)
            #pragma unroll
            for (int ni = 0; ni < 4; ++ni)
                #pragma unroll
                for (int r = 0; r < 4; ++r) {
                    int row = wm + mi*16 + (lane>>4)*4 + r;
                    int col = wn + ni*16 + (lane&15);
                    cL[row*136 + col] = f2b(acc[mi][ni][r]);
                }
        __syncthreads();
        unsigned short* D = (unsigned short*)Dout;
        #pragma unroll
        for (int it = 0; it < 8; ++it) {
            int f = it*256 + tid;
            int row = f >> 4, kp = f & 15;
            uint4 v = *(const uint4*)&cL[row*136 + kp*8];
            *(uint4*)&D[(arow0 + row)*(size_t)Npitch + n0 + kp*8] = v;
        }
    } else {
        float* D = (float*)Dout;
        #pragma unroll
        for (int mi = 0; mi < 4; ++mi)
            #pragma unroll
            for (int ni = 0; ni < 4; ++ni)
                #pragma unroll
                for (int r = 0; r < 4; ++r) {
                    int row = wm + mi*16 + (lane>>4)*4 + r;
                    int col = wn + ni*16 + (lane&15);
                    D[(arow0 + row)*(size_t)Npitch + n0 + col] = acc[mi][ni][r];
                }
    }
}

// ---------------- GN1 stats over bf16 h1t [l][512], 16 ch/group ----------------
__global__ __launch_bounds__(256) void k_gn1stats(
    const unsigned short* __restrict__ h, float* __restrict__ stats)
{
    __shared__ float sred[256], sred2[256];
    int tid = threadIdx.x;
    int b = blockIdx.x >> 5, g = blockIdx.x & 31;
    float s = 0.f, s2 = 0.f;
    for (int it = 0; it < 32; ++it) {
        int f = it*256 + tid;
        int l = f >> 1, half = f & 1;
        uint4 v = *(const uint4*)&h[((size_t)b*L4K + l)*512 + g*16 + half*8];
        unsigned int ws[4] = {v.x, v.y, v.z, v.w};
        #pragma unroll
        for (int u = 0; u < 4; ++u) {
            float a = b2f((unsigned short)(ws[u] & 0xFFFF));
            float c = b2f((unsigned short)(ws[u] >> 16));
            s += a + c; s2 = fmaf(a,a,s2); s2 = fmaf(c,c,s2);
        }
    }
    sred[tid] = s; sred2[tid] = s2; __syncthreads();
    for (int off = 128; off; off >>= 1) {
        if (tid < off) { sred[tid] += sred[tid+off]; sred2[tid] += sred2[tid+off]; }
        __syncthreads();
    }
    if (tid == 0) {
        float inv = 1.f/65536.f;
        float mn = sred[0]*inv;
        float var = sred2[0]*inv - mn*mn;
        stats[blockIdx.x*2]   = mn;
        stats[blockIdx.x*2+1] = rsqrtf(var + 1e-5f);
    }
}

// ---------------- K9: gn1 apply + exact gelu, in-place bf16 [l][512] --------
__global__ __launch_bounds__(256) void k9_gngelu(
    unsigned short* __restrict__ h, const float* __restrict__ stats,
    const float* __restrict__ g1, const float* __restrict__ b1)
{
    size_t idx = ((size_t)blockIdx.x*256 + threadIdx.x)*8;
    int o0 = (int)(idx & 511);
    int b = (int)(idx >> 21);
    int sg = b*32 + (o0 >> 4);
    float mn = stats[sg*2], rstd = stats[sg*2+1];
    uint4 v = *(uint4*)&h[idx];
    unsigned int ws[4] = {v.x, v.y, v.z, v.w};
    unsigned int out[4];
    #pragma unroll
    for (int u = 0; u < 4; ++u) {
        float a = b2f((unsigned short)(ws[u] & 0xFFFF));
        float c = b2f((unsigned short)(ws[u] >> 16));
        int o = o0 + u*2;
        float ta = (a-mn)*rstd*g1[o]   + b1[o];
        float tc = (c-mn)*rstd*g1[o+1] + b1[o+1];
        ta = 0.5f*ta*(1.f + erff(ta*0.70710678118654752f));
        tc = 0.5f*tc*(1.f + erff(tc*0.70710678118654752f));
        out[u] = f2b(ta) | ((unsigned)f2b(tc)<<16);
    }
    uint4 r; r.x = out[0]; r.y = out[1]; r.z = out[2]; r.w = out[3];
    *(uint4*)&h[idx] = r;
}

// ---------------- GN2 stats over fp32 h2t [l][128], 4 ch/group ----------------
__global__ __launch_bounds__(256) void k_gn2stats(
    const float* __restrict__ h, float* __restrict__ stats)
{
    __shared__ float sred[256], sred2[256];
    int tid = threadIdx.x;
    int b = blockIdx.x >> 5, g = blockIdx.x & 31;
    float s = 0.f, s2 = 0.f;
    for (int it = 0; it < 16; ++it) {
        int l = it*256 + tid;
        float4 v = ((const float4*)h)[((size_t)b*L4K + l)*32 + g];
        s += v.x+v.y+v.z+v.w;
        s2 = fmaf(v.x,v.x,s2); s2 = fmaf(v.y,v.y,s2); s2 = fmaf(v.z,v.z,s2); s2 = fmaf(v.w,v.w,s2);
    }
    sred[tid] = s; sred2[tid] = s2; __syncthreads();
    for (int off = 128; off; off >>= 1) {
        if (tid < off) { sred[tid] += sred[tid+off]; sred2[tid] += sred2[tid+off]; }
        __syncthreads();
    }
    if (tid == 0) {
        float inv = 1.f/16384.f;
        float mn = sred[0]*inv;
        float var = sred2[0]*inv - mn*mn;
        stats[blockIdx.x*2]   = mn;
        stats[blockIdx.x*2+1] = rsqrtf(var + 1e-5f);
    }
}

// ---------------- K12: out[c][l] = outp[c][l] + gn2(h2t[l][c]) (transpose) ----
__global__ __launch_bounds__(256) void k12_final(
    const float* __restrict__ outp, const float* __restrict__ h2t,
    const float* __restrict__ stats, const float* __restrict__ g2,
    const float* __restrict__ b2, float* __restrict__ out)
{
    __shared__ float T[32*33];
    int tid = threadIdx.x;
    int l0 = blockIdx.x*32, c0 = blockIdx.y*32, b = blockIdx.z;
    {
        int i = tid >> 3, jq = tid & 7;
        float4 v = ((const float4*)h2t)[((size_t)b*L4K + l0 + i)*32 + (c0>>2) + jq];
        int sg = b*32 + (c0>>2) + jq;
        float mn = stats[sg*2], rstd = stats[sg*2+1];
        int c = c0 + jq*4;
        T[(jq*4+0)*33 + i] = (v.x-mn)*rstd*g2[c+0] + b2[c+0];
        T[(jq*4+1)*33 + i] = (v.y-mn)*rstd*g2[c+1] + b2[c+1];
        T[(jq*4+2)*33 + i] = (v.z-mn)*rstd*g2[c+2] + b2[c+2];
        T[(jq*4+3)*33 + i] = (v.w-mn)*rstd*g2[c+3] + b2[c+3];
    }
    __syncthreads();
    {
        int c = tid >> 3, iq = tid & 7;
        size_t gi = ((size_t)b*128 + c0 + c)*1024 + (l0>>2) + iq;
        float4 o = ((const float4*)outp)[gi];
        float4 r;
        r.x = o.x + T[c*33 + iq*4 + 0];
        r.y = o.y + T[c*33 + iq*4 + 1];
        r.z = o.z + T[c*33 + iq*4 + 2];
        r.w = o.w + T[c*33 + iq*4 + 3];
        ((float4*)out)[gi] = r;
    }
}

extern "C" void kernel_launch(void* const* d_in, const int* in_sizes, int n_in,
                              void* d_out, int out_size, void* d_ws, size_t ws_size,
                              hipStream_t stream) {
    (void)in_sizes; (void)n_in; (void)out_size; (void)ws_size;
    const float* x    = (const float*)d_in[0];
    const float* png  = (const float*)d_in[1];
    const float* pnb  = (const float*)d_in[2];
    const float* biw  = (const float*)d_in[3];
    const float* bib  = (const float*)d_in[4];
    const float* ipw  = (const float*)d_in[5];
    const float* cw   = (const float*)d_in[6];
    const float* cb   = (const float*)d_in[7];
    const float* xpw  = (const float*)d_in[8];
    const float* dtw  = (const float*)d_in[9];
    const float* dtb  = (const float*)d_in[10];
    const float* alog = (const float*)d_in[11];
    const float* Dp   = (const float*)d_in[12];
    const float* opw  = (const float*)d_in[13];
    const float* pog  = (const float*)d_in[14];
    const float* pob  = (const float*)d_in[15];
    const float* bow  = (const float*)d_in[16];
    const float* bob  = (const float*)d_in[17];
    const float* rsp  = (const float*)d_in[18];
    const float* f1w  = (const float*)d_in[19];
    const float* g1g  = (const float*)d_in[20];
    const float* g1b  = (const float*)d_in[21];
    const float* f2w  = (const float*)d_in[22];
    const float* g2g  = (const float*)d_in[23];
    const float* g2b  = (const float*)d_in[24];

    char* ws = (char*)d_ws;
    // Phase 1 (mamba), peak 112 MiB. All [n][feature][4096] planes.
    float* S    = (float*)(ws + 0);            // 64 MB, dead after k5
    float* zc   = (float*)(ws + 67108864);     // 8 MB,  dead after k5
    float* zg   = (float*)(ws + 75497472);     // 16 MB, dead after k5
    float* xcp  = (float*)(ws + 92274688);     // 16 MB, dead after k2
    float* y    = (float*)(ws + 92274688);     // aliases xcp
    float* m    = (float*)(ws + 109051904);    // 8 MB (k5->k6)
    float* chA  = (float*)(ws + 109051904);                // 2 MB (pre-k5)
    float* chH  = (float*)(ws + 109051904 + 2097152);      // 2 MB
    float* hst  = (float*)(ws + 109051904 + 4194304);      // 2 MB
    // Phase 2 (post): all alias dead phase-1 regions
    float*          outp  = (float*)(ws + 0);              // 16 MB fp32 [c][l]
    unsigned short* outpb = (unsigned short*)(ws + 16777216); // 8 MB bf16 [l][c]
    unsigned short* h1tb  = (unsigned short*)(ws + 25165824); // 32 MB bf16 [l][512]
    float*          h2t   = (float*)(ws + 58720256);       // 16 MB fp32 [l][128]
    float*          st1   = (float*)(ws + 75497472);       // 2 KB (zg dead)
    float*          st2   = (float*)(ws + 75501568);

    k1_pre<<<dim3(128,8),256,0,stream>>>(x,png,pnb,biw,bib,ipw,zc,xcp,zg);
    k2_conv<<<dim3(32,32),128,0,stream>>>(xcp,cw,cb,xpw,dtw,dtb,S);
    k3a_local<<<dim3(NCH,32),512,0,stream>>>(S,alog,chA,chH);
    k3b_prefix<<<64,256,0,stream>>>(chA,chH,hst);
    k3c_emit<<<dim3(NCH,32),512,0,stream>>>(S,alog,hst,y);
    k5_out<<<512,256,0,stream>>>(y,S,zg,zc,Dp,opw,m);
    k6_post<<<dim3(64,8),256,0,stream>>>(m,x,pog,pob,bow,bob,rsp,outp,outpb);
    gemm_mfma<1,true><<<dim3(32,4,8),256,0,stream>>>(outpb,f1w,(void*)h1tb,128,512);
    k_gn1stats<<<256,256,0,stream>>>(h1tb,st1);
    k9_gngelu<<<8192,256,0,stream>>>(h1tb,st1,g1g,g1b);
    gemm_mfma<4,false><<<dim3(32,1,8),256,0,stream>>>(h1tb,f2w,(void*)h2t,512,128);
    k_gn2stats<<<256,256,0,stream>>>(h2t,st2);
    k12_final<<<dim3(128,4,8),256,0,stream>>>(outp,h2t,st2,g2g,g2b,(float*)d_out);
}

// Round 8
// 392.925 us; speedup vs baseline: 5.1244x; 1.1709x over previous
//
#include <hip/hip_runtime.h>
#include <hip/hip_bf16.h>
#include <math.h>

#define L4K 4096
#define NCH 32     // scan chunks over L
#define CL  128    // timesteps per chunk
#define SPN (128*4096)   // floats per n in S planes

typedef __attribute__((ext_vector_type(8))) short short8;
typedef __attribute__((ext_vector_type(4))) float f32x4;

__device__ __forceinline__ unsigned short f2b(float f) {
    unsigned int u = __float_as_uint(f);
    unsigned int r = u + 0x7FFFu + ((u >> 16) & 1u);
    return (unsigned short)(r >> 16);
}
__device__ __forceinline__ float b2f(unsigned short h) {
    return __uint_as_float(((unsigned int)h) << 16);
}
// sum over each 16-lane row via fused v_add_f32_dpp (bound_ctrl=true enables combine)
__device__ __forceinline__ float rowsum16(float p) {
    int t;
    t = __builtin_amdgcn_update_dpp(0, __float_as_int(p), 0x128, 0xf, 0xf, true);
    p += __int_as_float(t);
    t = __builtin_amdgcn_update_dpp(0, __float_as_int(p), 0x124, 0xf, 0xf, true);
    p += __int_as_float(t);
    t = __builtin_amdgcn_update_dpp(0, __float_as_int(p), 0x122, 0xf, 0xf, true);
    p += __int_as_float(t);
    t = __builtin_amdgcn_update_dpp(0, __float_as_int(p), 0x121, 0xf, 0xf, true);
    p += __int_as_float(t);
    return p;
}

// ---------------- K1: pre-LN + bott_in + in_proj (plane outputs) ----------------
__global__ __launch_bounds__(256) void k1_pre(
    const float* __restrict__ x, const float* __restrict__ png, const float* __restrict__ pnb,
    const float* __restrict__ biw, const float* __restrict__ bib, const float* __restrict__ ipw,
    float* __restrict__ zc, float* __restrict__ xcp, float* __restrict__ zg)
{
    __shared__ float xs[128*32];
    __shared__ float wl[64*128];
    __shared__ float zs[32*65];
    __shared__ float ipl[64*16];
    __shared__ float pngs[128], pnbs[128];
    int tid = threadIdx.x;
    int l0 = blockIdx.x*32, b = blockIdx.y;
    const float* xb = x + (size_t)b*128*L4K;
    for (int it = 0; it < 16; ++it) {
        int f = it*256 + tid; int c = f>>5, i = f&31;
        xs[f] = xb[(size_t)c*L4K + l0 + i];
    }
    for (int f = tid; f < 8192; f += 256) wl[f] = biw[f];
    for (int f = tid; f < 1024; f += 256) ipl[f] = ipw[f];
    if (tid < 128) { pngs[tid] = png[tid]; pnbs[tid] = pnb[tid]; }
    __syncthreads();
    int i = tid & 31, q = tid >> 5;
    float s = 0.f, s2 = 0.f;
    for (int c = 0; c < 128; ++c) { float v = xs[c*32+i]; s += v; s2 = fmaf(v,v,s2); }
    float mn = s*(1.f/128.f);
    float rstd = rsqrtf(s2*(1.f/128.f) - mn*mn + 1e-5f);
    float z[8];
    #pragma unroll
    for (int jj = 0; jj < 8; ++jj) z[jj] = bib[q*8+jj];
    for (int c = 0; c < 128; ++c) {
        float xv = (xs[c*32+i] - mn)*rstd*pngs[c] + pnbs[c];
        #pragma unroll
        for (int jj = 0; jj < 8; ++jj) z[jj] = fmaf(xv, wl[(q*8+jj)*128 + c], z[jj]);
    }
    #pragma unroll
    for (int jj = 0; jj < 8; ++jj) zs[i*65 + q*8 + jj] = z[jj];
    __syncthreads();
    if (tid < 128) {
        int i2 = tid & 31, g = tid >> 5;
        int n = g*8 + b; int l = l0 + i2;
        float zv[16];
        #pragma unroll
        for (int k = 0; k < 16; ++k) zv[k] = zs[i2*65 + g*16 + k];
        float* zcb = zc + ((size_t)n*16)*L4K + l;
        #pragma unroll
        for (int k = 0; k < 16; ++k) zcb[(size_t)k*L4K] = zv[k];
        float* xo = xcp + ((size_t)n*32)*L4K + l;
        float* zo = zg  + ((size_t)n*32)*L4K + l;
        #pragma unroll
        for (int o = 0; o < 64; ++o) {
            float a = 0.f;
            #pragma unroll
            for (int k = 0; k < 16; ++k) a = fmaf(zv[k], ipl[o*16+k], a);
            if (o < 32) xo[(size_t)o*L4K] = a; else zo[(size_t)(o-32)*L4K] = a;
        }
    }
}

// ---------------- K2: conv + silu + x_proj + dt -> S planes ----------------
// S planes per n (stride SPN): [0:32)=dt, [32:64)=dx, [64:80)=B, [80:96)=C, [96:128)=xc
__global__ __launch_bounds__(128) void k2_conv(
    const float* __restrict__ xcp, const float* __restrict__ cw, const float* __restrict__ cb,
    const float* __restrict__ xpw, const float* __restrict__ dtw, const float* __restrict__ dtb,
    float* __restrict__ S)
{
    __shared__ float xt[131*33];
    __shared__ float cwl[128], cbl[32], xpl[33*32], dtwl[32], dtbl[32];
    int tid = threadIdx.x;
    int t0 = blockIdx.x*128; int n = blockIdx.y;
    const float* xb = xcp + (size_t)n*32*L4K;
    #pragma unroll 4
    for (int d = 0; d < 32; ++d) {
        int t = t0 - 3 + tid;
        xt[tid*33 + d] = (t >= 0) ? xb[(size_t)d*L4K + t] : 0.f;
        if (tid < 3) {
            int r = 128 + tid; int t2 = t0 - 3 + r;
            xt[r*33 + d] = xb[(size_t)d*L4K + t2];
        }
    }
    if (tid < 128) cwl[tid] = cw[tid];
    if (tid < 32) { cbl[tid] = cb[tid]; dtwl[tid] = dtw[tid]; dtbl[tid] = dtb[tid]; }
    for (int f = tid; f < 33*32; f += 128) xpl[f] = xpw[f];
    __syncthreads();
    int t = t0 + tid;
    float xc[32];
    #pragma unroll
    for (int d = 0; d < 32; ++d) {
        float sv = cbl[d];
        #pragma unroll
        for (int k = 0; k < 4; ++k) sv = fmaf(cwl[d*4+k], xt[(tid+k)*33 + d], sv);
        xc[d] = sv / (1.f + __expf(-sv));
    }
    float dtr = 0.f; float Bv[16], Cv[16];
    #pragma unroll
    for (int dd = 0; dd < 32; ++dd) dtr = fmaf(xc[dd], xpl[dd], dtr);
    #pragma unroll
    for (int o = 0; o < 16; ++o) {
        float a = 0.f, a2 = 0.f;
        #pragma unroll
        for (int dd = 0; dd < 32; ++dd) {
            a  = fmaf(xc[dd], xpl[(1+o)*32+dd],  a);
            a2 = fmaf(xc[dd], xpl[(17+o)*32+dd], a2);
        }
        Bv[o] = a; Cv[o] = a2;
    }
    float* Sn = S + (size_t)n*SPN + t;
    #pragma unroll
    for (int d = 0; d < 32; ++d) {
        float dv = fmaf(dtr, dtwl[d], dtbl[d]);
        float sp = fmaxf(dv, 0.f) + log1pf(__expf(-fabsf(dv)));
        Sn[(size_t)d*L4K]      = sp;
        Sn[(size_t)(32+d)*L4K] = sp * xc[d];
        Sn[(size_t)(96+d)*L4K] = xc[d];
    }
    #pragma unroll
    for (int o = 0; o < 16; ++o) {
        Sn[(size_t)(64+o)*L4K] = Bv[o];
        Sn[(size_t)(80+o)*L4K] = Cv[o];
    }
}

// ---------------- K3a: chunk-local scan (LDS pair-staged) ----------------
// 512 threads = 32 d x 16 s; full 128-t chunk staged once.
__global__ __launch_bounds__(512) void k3a_local(
    const float* __restrict__ S, const float* __restrict__ alog,
    float* __restrict__ chunkA, float* __restrict__ chunkH)
{
    __shared__ float2 pDT[32*130];   // (dt,dx)[d][t], stride 130
    __shared__ float  pB[16*132];    // B[s][t], stride 132
    int tid = threadIdx.x;
    int d = tid >> 4, s = tid & 15;
    int chunk = blockIdx.x, n = blockIdx.y;
    float A = -__expf(alog[d*16 + s]);
    const float* base = S + (size_t)n*SPN + (size_t)chunk*CL;
    {   // stage (dt,dx) pairs: thread = (sd, j), 8 t each
        int sd = tid >> 4, j = tid & 15;
        const float* dtp = base + (size_t)sd*L4K + j*8;
        const float* dxp = base + (size_t)(32+sd)*L4K + j*8;
        float4 a0 = *(const float4*)(dtp);
        float4 a1 = *(const float4*)(dtp+4);
        float4 b0 = *(const float4*)(dxp);
        float4 b1 = *(const float4*)(dxp+4);
        float2* w = pDT + sd*130 + j*8;
        *(float4*)(w+0) = make_float4(a0.x,b0.x,a0.y,b0.y);
        *(float4*)(w+2) = make_float4(a0.z,b0.z,a0.w,b0.w);
        *(float4*)(w+4) = make_float4(a1.x,b1.x,a1.y,b1.y);
        *(float4*)(w+6) = make_float4(a1.z,b1.z,a1.w,b1.w);
    }
    if (tid < 256) {   // stage B singles: thread = (ss, j), 8 t each
        int ss = tid >> 4, j = tid & 15;
        const float* bp = base + (size_t)(64+ss)*L4K + j*8;
        float4 v0 = *(const float4*)(bp);
        float4 v1 = *(const float4*)(bp+4);
        float* w = pB + ss*132 + j*8;
        *(float4*)(w+0) = v0;
        *(float4*)(w+4) = v1;
    }
    __syncthreads();
    float h = 0.f, ap = 1.f;
    #pragma unroll 4
    for (int t = 0; t < CL; ++t) {
        float2 dd = pDT[d*130 + t];
        float Bv = pB[s*132 + t];
        float dA = __expf(dd.x * A);
        h = fmaf(dA, h, dd.y * Bv);
        ap *= dA;
    }
    size_t idx = (size_t)chunk*16384 + n*512 + tid;
    chunkA[idx] = ap;
    chunkH[idx] = h;
}

// ---------------- K3b: prefix across chunks ----------------
__global__ __launch_bounds__(256) void k3b_prefix(
    const float* __restrict__ chunkA, const float* __restrict__ chunkH,
    float* __restrict__ hstart)
{
    int nds = blockIdx.x*256 + threadIdx.x;
    float h = 0.f;
    hstart[nds] = 0.f;
    for (int c = 0; c < NCH-1; ++c) {
        h = fmaf(h, chunkA[(size_t)c*16384 + nds], chunkH[(size_t)c*16384 + nds]);
        hstart[(size_t)(c+1)*16384 + nds] = h;
    }
}

// ---------------- K3c: recompute with start state, emit y planes ------------
__global__ __launch_bounds__(512) void k3c_emit(
    const float* __restrict__ S, const float* __restrict__ alog,
    const float* __restrict__ hstart, float* __restrict__ y)
{
    __shared__ float2 pDT[32*130];   // (dt,dx)[d][t]
    __shared__ float2 pBC[16*130];   // (B,C)[s][t]
    int tid = threadIdx.x;
    int d = tid >> 4, s = tid & 15;
    int chunk = blockIdx.x, n = blockIdx.y;
    float A = -__expf(alog[d*16 + s]);
    const float* base = S + (size_t)n*SPN + (size_t)chunk*CL;
    float h = hstart[(size_t)chunk*16384 + n*512 + tid];
    {   // stage (dt,dx)
        int sd = tid >> 4, j = tid & 15;
        const float* dtp = base + (size_t)sd*L4K + j*8;
        const float* dxp = base + (size_t)(32+sd)*L4K + j*8;
        float4 a0 = *(const float4*)(dtp);
        float4 a1 = *(const float4*)(dtp+4);
        float4 b0 = *(const float4*)(dxp);
        float4 b1 = *(const float4*)(dxp+4);
        float2* w = pDT + sd*130 + j*8;
        *(float4*)(w+0) = make_float4(a0.x,b0.x,a0.y,b0.y);
        *(float4*)(w+2) = make_float4(a0.z,b0.z,a0.w,b0.w);
        *(float4*)(w+4) = make_float4(a1.x,b1.x,a1.y,b1.y);
        *(float4*)(w+6) = make_float4(a1.z,b1.z,a1.w,b1.w);
    }
    if (tid < 256) {   // stage (B,C)
        int ss = tid >> 4, j = tid & 15;
        const float* bp = base + (size_t)(64+ss)*L4K + j*8;
        const float* cp = base + (size_t)(80+ss)*L4K + j*8;
        float4 v0 = *(const float4*)(bp);
        float4 v1 = *(const float4*)(bp+4);
        float4 c0 = *(const float4*)(cp);
        float4 c1 = *(const float4*)(cp+4);
        float2* w = pBC + ss*130 + j*8;
        *(float4*)(w+0) = make_float4(v0.x,c0.x,v0.y,c0.y);
        *(float4*)(w+2) = make_float4(v0.z,c0.z,v0.w,c0.w);
        *(float4*)(w+4) = make_float4(v1.x,c1.x,v1.y,c1.y);
        *(float4*)(w+6) = make_float4(v1.z,c1.z,v1.w,c1.w);
    }
    __syncthreads();
    float4* yb = (float4*)(y + ((size_t)n*32 + d)*L4K + (size_t)chunk*CL);
    for (int i = 0; i < CL/4; ++i) {
        float4 yv;
        #pragma unroll
        for (int u = 0; u < 4; ++u) {
            int t = i*4 + u;
            float2 dd = pDT[d*130 + t];
            float2 bc = pBC[s*130 + t];
            float dA = __expf(dd.x * A);
            h = fmaf(dA, h, dd.y * bc.x);
            ((float*)&yv)[u] = rowsum16(h * bc.y);
        }
        if (s == 0) yb[i] = yv;
    }
}

// ---------------- K5: gate + out_proj + residual -> m planes ----------------
__global__ __launch_bounds__(256) void k5_out(
    const float* __restrict__ y, const float* __restrict__ S, const float* __restrict__ zg,
    const float* __restrict__ zc, const float* __restrict__ Dp, const float* __restrict__ opw,
    float* __restrict__ m)
{
    int id = blockIdx.x*256 + threadIdx.x;
    int n = id >> 12, t = id & 4095;
    const float* yb  = y  + (size_t)n*32*L4K + t;
    const float* xcb = S  + (size_t)n*SPN + (size_t)96*L4K + t;
    const float* zgb = zg + (size_t)n*32*L4K + t;
    const float* zcb = zc + (size_t)n*16*L4K + t;
    float v[32];
    #pragma unroll
    for (int dd = 0; dd < 32; ++dd) {
        float g = zgb[(size_t)dd*L4K];
        float sig = 1.f/(1.f + __expf(-g));
        v[dd] = (yb[(size_t)dd*L4K] + xcb[(size_t)dd*L4K]*Dp[dd]) * (g*sig);
    }
    int b = n & 7, g4 = n >> 3;
    float* mp = m + ((size_t)b*64 + g4*16)*L4K + t;
    #pragma unroll
    for (int j = 0; j < 16; ++j) {
        float a = zcb[(size_t)j*L4K];
        #pragma unroll
        for (int dd = 0; dd < 32; ++dd) a = fmaf(v[dd], opw[j*32+dd], a);
        mp[(size_t)j*L4K] = a;
    }
}

// ---------------- K6: post-LN + bott_out; outp fp32 [c][l] + bf16 [l][c] ----
__global__ __launch_bounds__(256) void k6_post(
    const float* __restrict__ m, const float* __restrict__ x,
    const float* __restrict__ pog, const float* __restrict__ pob,
    const float* __restrict__ bow, const float* __restrict__ bob,
    const float* __restrict__ rsp, float* __restrict__ outp,
    unsigned short* __restrict__ outpb)
{
    __shared__ float ms[64*65];
    __shared__ float wl[128*64];
    __shared__ float pogs[64], pobs[64];
    int tid = threadIdx.x;
    int l0 = blockIdx.x*64, b = blockIdx.y;
    for (int f = tid; f < 4096; f += 256) {
        int i = f & 63, j = f >> 6;
        ms[i*65 + j] = m[((size_t)b*64 + j)*L4K + l0 + i];
    }
    for (int f = tid; f < 8192; f += 256) wl[f] = bow[f];
    if (tid < 64) { pogs[tid] = pog[tid]; pobs[tid] = pob[tid]; }
    __syncthreads();
    float rs = rsp[0];
    int i = tid & 63, q = tid >> 6;
    float s = 0.f, s2 = 0.f;
    for (int j = 0; j < 64; ++j) { float v = ms[i*65+j]; s += v; s2 = fmaf(v,v,s2); }
    float mn = s*(1.f/64.f);
    float rstd = rsqrtf(s2*(1.f/64.f) - mn*mn + 1e-5f);
    float acc[32];
    #pragma unroll
    for (int cc = 0; cc < 32; ++cc) acc[cc] = bob[q*32+cc];
    for (int j = 0; j < 64; ++j) {
        float v = (ms[i*65+j]-mn)*rstd*pogs[j] + pobs[j];
        #pragma unroll
        for (int cc = 0; cc < 32; ++cc) acc[cc] = fmaf(v, wl[(q*32+cc)*64+j], acc[cc]);
    }
    const float* xb = x + (size_t)b*128*L4K + l0 + i;
    float* ob = outp + (size_t)b*128*L4K + l0 + i;
    unsigned short pk[32];
    #pragma unroll
    for (int cc = 0; cc < 32; ++cc) {
        int c = q*32 + cc;
        float val = 2.f*xb[(size_t)c*L4K] + acc[cc]*rs;
        ob[(size_t)c*L4K] = val;
        pk[cc] = f2b(val);
    }
    uint4* op = (uint4*)&outpb[((size_t)b*L4K + l0 + i)*128 + q*32];
    #pragma unroll
    for (int u = 0; u < 4; ++u) {
        uint4 v;
        v.x = pk[u*8+0] | ((unsigned)pk[u*8+1]<<16);
        v.y = pk[u*8+2] | ((unsigned)pk[u*8+3]<<16);
        v.z = pk[u*8+4] | ((unsigned)pk[u*8+5]<<16);
        v.w = pk[u*8+6] | ((unsigned)pk[u*8+7]<<16);
        op[u] = v;
    }
}

// ---------------- MFMA GEMM: D[l][n] = A[l][k] * W[n][k]^T ----------------
template<int KCHUNKS, bool OUT_BF16>
__global__ __launch_bounds__(256) void gemm_mfma(
    const unsigned short* __restrict__ Ab, const float* __restrict__ Wg,
    void* __restrict__ Dout, int Kpitch, int Npitch)
{
    __shared__ char lds[65536];
    int tid = threadIdx.x;
    int lane = tid & 63, w = tid >> 6;
    int l0 = blockIdx.x * 128, n0 = blockIdx.y * 128, b = blockIdx.z;
    size_t arow0 = (size_t)b*L4K + l0;
    int wm = (w>>1)*64, wn = (w&1)*64;
    f32x4 acc[4][4] = {};
    char* aL = lds;
    char* wL = lds + 32768;
    for (int kc = 0; kc < KCHUNKS; ++kc) {
        if (kc) __syncthreads();
        #pragma unroll
        for (int it = 0; it < 8; ++it) {
            int f = it*256 + tid;
            int row = f >> 4, kp = f & 15;
            uint4 v = *(const uint4*)&Ab[(arow0 + row)*(size_t)Kpitch + kc*128 + kp*8];
            int off = row*256 + kp*16; off ^= (row&7)<<4;
            *(uint4*)(aL + off) = v;
        }
        #pragma unroll
        for (int it = 0; it < 16; ++it) {
            int f = it*256 + tid;
            int row = f >> 5, kg = f & 31;
            float4 v = *(const float4*)&Wg[(size_t)(n0+row)*(KCHUNKS*128) + kc*128 + kg*4];
            uint2 p;
            p.x = f2b(v.x) | ((unsigned)f2b(v.y)<<16);
            p.y = f2b(v.z) | ((unsigned)f2b(v.w)<<16);
            int off = row*256 + kg*8; off ^= (row&7)<<4;
            *(uint2*)(wL + off) = p;
        }
        __syncthreads();
        #pragma unroll
        for (int ks = 0; ks < 4; ++ks) {
            short8 af[4], wf[4];
            int kb = ks*64 + (lane>>4)*16;
            #pragma unroll
            for (int mi = 0; mi < 4; ++mi) {
                int row = wm + mi*16 + (lane&15);
                int off = row*256 + kb; off ^= (row&7)<<4;
                af[mi] = *(const short8*)(aL + off);
            }
            #pragma unroll
            for (int ni = 0; ni < 4; ++ni) {
                int row = wn + ni*16 + (lane&15);
                int off = row*256 + kb; off ^= (row&7)<<4;
                wf[ni] = *(const short8*)(wL + off);
            }
            #pragma unroll
            for (int mi = 0; mi < 4; ++mi)
                #pragma unroll
                for (int ni = 0; ni < 4; ++ni)
                    acc[mi][ni] = __builtin_amdgcn_mfma_f32_16x16x32_bf16(af[mi], wf[ni], acc[mi][ni], 0, 0, 0);
        }
    }
    if (OUT_BF16) {
        __syncthreads();
        unsigned short* cL = (unsigned short*)lds;   // [128][136]
        #pragma unroll
        for (int mi = 0; mi < 4; ++mi)
            #pragma unroll
            for (int ni = 0; ni < 4; ++ni)
                #pragma unroll
                for (int r = 0; r < 4; ++r) {
                    int row = wm + mi*16 + (lane>>4)*4 + r;
                    int col = wn + ni*16 + (lane&15);
                    cL[row*136 + col] = f2b(acc[mi][ni][r]);
                }
        __syncthreads();
        unsigned short* D = (unsigned short*)Dout;
        #pragma unroll
        for (int it = 0; it < 8; ++it) {
            int f = it*256 + tid;
            int row = f >> 4, kp = f & 15;
            uint4 v = *(const uint4*)&cL[row*136 + kp*8];
            *(uint4*)&D[(arow0 + row)*(size_t)Npitch + n0 + kp*8] = v;
        }
    } else {
        float* D = (float*)Dout;
        #pragma unroll
        for (int mi = 0; mi < 4; ++mi)
            #pragma unroll
            for (int ni = 0; ni < 4; ++ni)
                #pragma unroll
                for (int r = 0; r < 4; ++r) {
                    int row = wm + mi*16 + (lane>>4)*4 + r;
                    int col = wn + ni*16 + (lane&15);
                    D[(arow0 + row)*(size_t)Npitch + n0 + col] = acc[mi][ni][r];
                }
    }
}

// ---------------- GN1 stats over bf16 h1t [l][512], 16 ch/group ----------------
__global__ __launch_bounds__(256) void k_gn1stats(
    const unsigned short* __restrict__ h, float* __restrict__ stats)
{
    __shared__ float sred[256], sred2[256];
    int tid = threadIdx.x;
    int b = blockIdx.x >> 5, g = blockIdx.x & 31;
    float s = 0.f, s2 = 0.f;
    for (int it = 0; it < 32; ++it) {
        int f = it*256 + tid;
        int l = f >> 1, half = f & 1;
        uint4 v = *(const uint4*)&h[((size_t)b*L4K + l)*512 + g*16 + half*8];
        unsigned int ws[4] = {v.x, v.y, v.z, v.w};
        #pragma unroll
        for (int u = 0; u < 4; ++u) {
            float a = b2f((unsigned short)(ws[u] & 0xFFFF));
            float c = b2f((unsigned short)(ws[u] >> 16));
            s += a + c; s2 = fmaf(a,a,s2); s2 = fmaf(c,c,s2);
        }
    }
    sred[tid] = s; sred2[tid] = s2; __syncthreads();
    for (int off = 128; off; off >>= 1) {
        if (tid < off) { sred[tid] += sred[tid+off]; sred2[tid] += sred2[tid+off]; }
        __syncthreads();
    }
    if (tid == 0) {
        float inv = 1.f/65536.f;
        float mn = sred[0]*inv;
        float var = sred2[0]*inv - mn*mn;
        stats[blockIdx.x*2]   = mn;
        stats[blockIdx.x*2+1] = rsqrtf(var + 1e-5f);
    }
}

// ---------------- K9: gn1 apply + exact gelu, in-place bf16 [l][512] --------
__global__ __launch_bounds__(256) void k9_gngelu(
    unsigned short* __restrict__ h, const float* __restrict__ stats,
    const float* __restrict__ g1, const float* __restrict__ b1)
{
    size_t idx = ((size_t)blockIdx.x*256 + threadIdx.x)*8;
    int o0 = (int)(idx & 511);
    int b = (int)(idx >> 21);
    int sg = b*32 + (o0 >> 4);
    float mn = stats[sg*2], rstd = stats[sg*2+1];
    uint4 v = *(uint4*)&h[idx];
    unsigned int ws[4] = {v.x, v.y, v.z, v.w};
    unsigned int out[4];
    #pragma unroll
    for (int u = 0; u < 4; ++u) {
        float a = b2f((unsigned short)(ws[u] & 0xFFFF));
        float c = b2f((unsigned short)(ws[u] >> 16));
        int o = o0 + u*2;
        float ta = (a-mn)*rstd*g1[o]   + b1[o];
        float tc = (c-mn)*rstd*g1[o+1] + b1[o+1];
        ta = 0.5f*ta*(1.f + erff(ta*0.70710678118654752f));
        tc = 0.5f*tc*(1.f + erff(tc*0.70710678118654752f));
        out[u] = f2b(ta) | ((unsigned)f2b(tc)<<16);
    }
    uint4 r; r.x = out[0]; r.y = out[1]; r.z = out[2]; r.w = out[3];
    *(uint4*)&h[idx] = r;
}

// ---------------- GN2 stats over fp32 h2t [l][128], 4 ch/group ----------------
__global__ __launch_bounds__(256) void k_gn2stats(
    const float* __restrict__ h, float* __restrict__ stats)
{
    __shared__ float sred[256], sred2[256];
    int tid = threadIdx.x;
    int b = blockIdx.x >> 5, g = blockIdx.x & 31;
    float s = 0.f, s2 = 0.f;
    for (int it = 0; it < 16; ++it) {
        int l = it*256 + tid;
        float4 v = ((const float4*)h)[((size_t)b*L4K + l)*32 + g];
        s += v.x+v.y+v.z+v.w;
        s2 = fmaf(v.x,v.x,s2); s2 = fmaf(v.y,v.y,s2); s2 = fmaf(v.z,v.z,s2); s2 = fmaf(v.w,v.w,s2);
    }
    sred[tid] = s; sred2[tid] = s2; __syncthreads();
    for (int off = 128; off; off >>= 1) {
        if (tid < off) { sred[tid] += sred[tid+off]; sred2[tid] += sred2[tid+off]; }
        __syncthreads();
    }
    if (tid == 0) {
        float inv = 1.f/16384.f;
        float mn = sred[0]*inv;
        float var = sred2[0]*inv - mn*mn;
        stats[blockIdx.x*2]   = mn;
        stats[blockIdx.x*2+1] = rsqrtf(var + 1e-5f);
    }
}

// ---------------- K12: out[c][l] = outp[c][l] + gn2(h2t[l][c]) (transpose) ----
__global__ __launch_bounds__(256) void k12_final(
    const float* __restrict__ outp, const float* __restrict__ h2t,
    const float* __restrict__ stats, const float* __restrict__ g2,
    const float* __restrict__ b2, float* __restrict__ out)
{
    __shared__ float T[32*33];
    int tid = threadIdx.x;
    int l0 = blockIdx.x*32, c0 = blockIdx.y*32, b = blockIdx.z;
    {
        int i = tid >> 3, jq = tid & 7;
        float4 v = ((const float4*)h2t)[((size_t)b*L4K + l0 + i)*32 + (c0>>2) + jq];
        int sg = b*32 + (c0>>2) + jq;
        float mn = stats[sg*2], rstd = stats[sg*2+1];
        int c = c0 + jq*4;
        T[(jq*4+0)*33 + i] = (v.x-mn)*rstd*g2[c+0] + b2[c+0];
        T[(jq*4+1)*33 + i] = (v.y-mn)*rstd*g2[c+1] + b2[c+1];
        T[(jq*4+2)*33 + i] = (v.z-mn)*rstd*g2[c+2] + b2[c+2];
        T[(jq*4+3)*33 + i] = (v.w-mn)*rstd*g2[c+3] + b2[c+3];
    }
    __syncthreads();
    {
        int c = tid >> 3, iq = tid & 7;
        size_t gi = ((size_t)b*128 + c0 + c)*1024 + (l0>>2) + iq;
        float4 o = ((const float4*)outp)[gi];
        float4 r;
        r.x = o.x + T[c*33 + iq*4 + 0];
        r.y = o.y + T[c*33 + iq*4 + 1];
        r.z = o.z + T[c*33 + iq*4 + 2];
        r.w = o.w + T[c*33 + iq*4 + 3];
        ((float4*)out)[gi] = r;
    }
}

extern "C" void kernel_launch(void* const* d_in, const int* in_sizes, int n_in,
                              void* d_out, int out_size, void* d_ws, size_t ws_size,
                              hipStream_t stream) {
    (void)in_sizes; (void)n_in; (void)out_size; (void)ws_size;
    const float* x    = (const float*)d_in[0];
    const float* png  = (const float*)d_in[1];
    const float* pnb  = (const float*)d_in[2];
    const float* biw  = (const float*)d_in[3];
    const float* bib  = (const float*)d_in[4];
    const float* ipw  = (const float*)d_in[5];
    const float* cw   = (const float*)d_in[6];
    const float* cb   = (const float*)d_in[7];
    const float* xpw  = (const float*)d_in[8];
    const float* dtw  = (const float*)d_in[9];
    const float* dtb  = (const float*)d_in[10];
    const float* alog = (const float*)d_in[11];
    const float* Dp   = (const float*)d_in[12];
    const float* opw  = (const float*)d_in[13];
    const float* pog  = (const float*)d_in[14];
    const float* pob  = (const float*)d_in[15];
    const float* bow  = (const float*)d_in[16];
    const float* bob  = (const float*)d_in[17];
    const float* rsp  = (const float*)d_in[18];
    const float* f1w  = (const float*)d_in[19];
    const float* g1g  = (const float*)d_in[20];
    const float* g1b  = (const float*)d_in[21];
    const float* f2w  = (const float*)d_in[22];
    const float* g2g  = (const float*)d_in[23];
    const float* g2b  = (const float*)d_in[24];

    char* ws = (char*)d_ws;
    // Phase 1 (mamba), peak 112 MiB. All [n][feature][4096] planes.
    float* S    = (float*)(ws + 0);            // 64 MB, dead after k5
    float* zc   = (float*)(ws + 67108864);     // 8 MB,  dead after k5
    float* zg   = (float*)(ws + 75497472);     // 16 MB, dead after k5
    float* xcp  = (float*)(ws + 92274688);     // 16 MB, dead after k2
    float* y    = (float*)(ws + 92274688);     // aliases xcp
    float* m    = (float*)(ws + 109051904);    // 8 MB (k5->k6)
    float* chA  = (float*)(ws + 109051904);                // 2 MB (pre-k5)
    float* chH  = (float*)(ws + 109051904 + 2097152);      // 2 MB
    float* hst  = (float*)(ws + 109051904 + 4194304);      // 2 MB
    // Phase 2 (post): all alias dead phase-1 regions
    float*          outp  = (float*)(ws + 0);              // 16 MB fp32 [c][l]
    unsigned short* outpb = (unsigned short*)(ws + 16777216); // 8 MB bf16 [l][c]
    unsigned short* h1tb  = (unsigned short*)(ws + 25165824); // 32 MB bf16 [l][512]
    float*          h2t   = (float*)(ws + 58720256);       // 16 MB fp32 [l][128]
    float*          st1   = (float*)(ws + 75497472);       // 2 KB (zg dead)
    float*          st2   = (float*)(ws + 75501568);

    k1_pre<<<dim3(128,8),256,0,stream>>>(x,png,pnb,biw,bib,ipw,zc,xcp,zg);
    k2_conv<<<dim3(32,32),128,0,stream>>>(xcp,cw,cb,xpw,dtw,dtb,S);
    k3a_local<<<dim3(NCH,32),512,0,stream>>>(S,alog,chA,chH);
    k3b_prefix<<<64,256,0,stream>>>(chA,chH,hst);
    k3c_emit<<<dim3(NCH,32),512,0,stream>>>(S,alog,hst,y);
    k5_out<<<512,256,0,stream>>>(y,S,zg,zc,Dp,opw,m);
    k6_post<<<dim3(64,8),256,0,stream>>>(m,x,pog,pob,bow,bob,rsp,outp,outpb);
    gemm_mfma<1,true><<<dim3(32,4,8),256,0,stream>>>(outpb,f1w,(void*)h1tb,128,512);
    k_gn1stats<<<256,256,0,stream>>>(h1tb,st1);
    k9_gngelu<<<8192,256,0,stream>>>(h1tb,st1,g1g,g1b);
    gemm_mfma<4,false><<<dim3(32,1,8),256,0,stream>>>(h1tb,f2w,(void*)h2t,512,128);
    k_gn2stats<<<256,256,0,stream>>>(h2t,st2);
    k12_final<<<dim3(128,4,8),256,0,stream>>>(outp,h2t,st2,g2g,g2b,(float*)d_out);
}